// Round 5
// baseline (346.120 us; speedup 1.0000x reference)
//
#include <hip/hip_runtime.h>
#include <math.h>

// ---------------------------------------------------------------------------
// CrossViewAttention — 5-node pipeline with per-transformer-block megakernel.
// prep -> KV gemm (both blocks) -> mega0 -> mega1 -> out
// B=1, C=256, M=4096, W=128, H=32, BLOCKS=2, HEADS=8, DH=32
// ---------------------------------------------------------------------------

#define C_DIM 256
#define M_DIM 4096
#define W_DIM 128
#define H_DIM 32
#define ATT_SCALE 0.17677669529663687f  // 1/sqrt(32)

typedef __attribute__((ext_vector_type(8))) short short8;
typedef __attribute__((ext_vector_type(4))) short short4v;
typedef __attribute__((ext_vector_type(4))) float floatx4;

__device__ __forceinline__ unsigned short f2bf(float f) {
    unsigned u = __float_as_uint(f);
    unsigned r = (u + 0x7fffu + ((u >> 16) & 1u)) >> 16;
    return (unsigned short)r;
}
__device__ __forceinline__ float gelu_exact(float x) {
    return 0.5f * x * (1.0f + erff(x * 0.70710678118654752f));
}

// ======================= mega prep kernel ==================================
// roles by blockIdx.x:
//   [0,256)    transpose grd2sat (C,M) -> xcur (M,C)
//   [256,384)  yhat: LN over C of grd_x columns -> yhat[(w*32+h)][c]
//   [384,1408) weight transpose+scale+convert: W'[n][k] = ln_w[k]*W[k][n] bf16
//   [1408,1418) folded biases: out[col] = base[col] + sum_k ln_b[k]*W[k][col]
//   1418       bucket sort of queries by wl=floor(u) into 16-query chunks
struct PrepArgs {
    const float* grd2sat; float* xcur;
    const float* grd_x;   float* yhat;
    const float* u; int* perm; int4* chunks; int* nchunks;
    const float* win[12]; unsigned short* wout[12]; const float* wlnw[12];
    int wR[12], wC[12], wbase[13];
    const float* fW[10]; const float* flnb[10]; const float* fbase[10];
    float* fout[10];
    int fN[10], fwcol[10], focol[10];
};

__global__ __launch_bounds__(256) void prep_kernel(PrepArgs a) {
    __shared__ float smemf[9024];
    int b = blockIdx.x, t = threadIdx.x;
    if (b < 256) {
        float (*tile)[65] = (float(*)[65])smemf;
        int m0 = (b & 63) << 6, c0 = (b >> 6) << 6;
        for (int it = 0; it < 16; ++it) {
            int idx = it * 256 + t;
            int co = idx >> 6, mo = idx & 63;
            tile[co][mo] = a.grd2sat[(size_t)(c0 + co) * M_DIM + m0 + mo];
        }
        __syncthreads();
        for (int it = 0; it < 16; ++it) {
            int idx = it * 256 + t;
            int mo = idx >> 6, co = idx & 63;
            a.xcur[(size_t)(m0 + mo) * C_DIM + c0 + co] = tile[co][mo];
        }
    } else if (b < 384) {
        int idx = b - 256;
        int h = idx & 31, w0 = (idx >> 5) << 5;
        float (*tile)[33] = (float(*)[33])smemf;
        float (*ps)[32] = (float(*)[32])(smemf + 8448);
        float (*pss)[32] = (float(*)[32])(smemf + 8704);
        float* mu_s = smemf + 8960;
        float* rs_s = smemf + 8992;
        int wo = t & 31, cb = t >> 5;
        for (int it = 0; it < 32; ++it) {
            int c = it * 8 + cb;
            tile[c][wo] = a.grd_x[(size_t)c * (H_DIM * W_DIM) + h * W_DIM + w0 + wo];
        }
        __syncthreads();
        {
            int w = t & 31, part = t >> 5;
            float s = 0.f, ss = 0.f;
            for (int c = part * 32; c < part * 32 + 32; ++c) {
                float x = tile[c][w];
                s += x; ss += x * x;
            }
            ps[part][w] = s; pss[part][w] = ss;
        }
        __syncthreads();
        if (t < 32) {
            float s = 0.f, ss = 0.f;
            for (int p = 0; p < 8; ++p) { s += ps[p][t]; ss += pss[p][t]; }
            float mu = s * (1.f / 256.f);
            float var = ss * (1.f / 256.f) - mu * mu;
            mu_s[t] = mu;
            rs_s[t] = rsqrtf(var + 1e-5f);
        }
        __syncthreads();
        for (int jj = 0; jj < 32; ++jj) {
            float mu = mu_s[jj], rs = rs_s[jj];
            a.yhat[((size_t)(w0 + jj) * H_DIM + h) * C_DIM + t] =
                (tile[t][jj] - mu) * rs;
        }
    } else if (b < 1408) {
        int wI = b - 384;
        int e = 0;
        while (wI >= a.wbase[e + 1]) ++e;
        int tl = wI - a.wbase[e];
        int tilesC = a.wC[e] >> 5;
        int tr = tl / tilesC, tc = tl - tr * tilesC;
        int r0 = tr << 5, c0 = tc << 5;
        const float* in = a.win[e];
        unsigned short* out = a.wout[e];
        const float* lnw = a.wlnw[e];
        int R = a.wR[e], Cc = a.wC[e];
        float (*tile)[33] = (float(*)[33])smemf;
        int rl = t >> 3, cq = (t & 7) << 2;
        float4 v = *(const float4*)&in[(size_t)(r0 + rl) * Cc + c0 + cq];
        if (lnw) {
            float s = lnw[r0 + rl];
            v.x *= s; v.y *= s; v.z *= s; v.w *= s;
        }
        tile[rl][cq + 0] = v.x;
        tile[rl][cq + 1] = v.y;
        tile[rl][cq + 2] = v.z;
        tile[rl][cq + 3] = v.w;
        __syncthreads();
        int cl = t >> 3, rq = (t & 7) << 2;
        ushort4 o;
        o.x = f2bf(tile[rq + 0][cl]);
        o.y = f2bf(tile[rq + 1][cl]);
        o.z = f2bf(tile[rq + 2][cl]);
        o.w = f2bf(tile[rq + 3][cl]);
        *(ushort4*)&out[(size_t)(c0 + cl) * R + r0 + rq] = o;
    } else if (b < 1418) {
        int jj = b - 1408;
        int N = a.fN[jj];
        int wcol = a.fwcol[jj] + t;
        const float* W = a.fW[jj];
        const float* lb = a.flnb[jj];
        float s = a.fbase[jj] ? a.fbase[jj][wcol] : 0.f;
        for (int k = 0; k < 256; ++k) s += lb[k] * W[(size_t)k * N + wcol];
        a.fout[jj][a.focol[jj] + t] = s;
    } else {
        // ---- bucket sort by wl = floor(u[m]) in [0,126]; 16-query chunks
        int* hist = (int*)smemf;
        int* cur = (int*)smemf + 128;
        unsigned short* wlb = (unsigned short*)((int*)smemf + 256);
        if (t < 128) hist[t] = 0;
        __syncthreads();
        for (int it = 0; it < 16; ++it) {
            int m = it * 256 + t;
            int wl = (int)floorf(a.u[m]);
            wl = max(0, min(wl, 126));
            wlb[m] = (unsigned short)wl;
            atomicAdd(&hist[wl], 1);
        }
        __syncthreads();
        if (t == 0) {
            int run = 0, nc = 0;
            for (int bkt = 0; bkt < 127; ++bkt) {
                int c = hist[bkt];
                cur[bkt] = run;
                int q0 = run;
                while (c > 0) {
                    int take = min(c, 16);
                    a.chunks[nc] = make_int4(bkt, q0, take, 0);
                    ++nc; q0 += take; c -= take;
                }
                run += hist[bkt];
            }
            *a.nchunks = nc;
        }
        __syncthreads();
        for (int it = 0; it < 16; ++it) {
            int m = it * 256 + t;
            int wl = wlb[m];
            int pos = atomicAdd(&cur[wl], 1);
            a.perm[pos] = m;
        }
    }
}

// ======================= KV table GEMM (both blocks) =======================
// A = yhat fp32 [4096][256]; Bt = [Wk';Wv'] bf16 [512][256]; bias 512-wide.
// cols <256 -> Ktab bf16 [m][256]; cols >=256 -> Vt bf16 [(col-256)][4096].
struct KVJob {
    const float* A; const unsigned short* Bt; const float* bias;
    unsigned short* Kt; unsigned short* Vt;
};

__global__ __launch_bounds__(256) void kv_gemm(KVJob j0, KVJob j1) {
    __shared__ short As[32][264];
    __shared__ short Bs[64][264];
    const KVJob j = ((int)blockIdx.y < 8) ? j0 : j1;
    int by = ((int)blockIdx.y < 8) ? blockIdx.y : blockIdx.y - 8;
    int t = threadIdx.x;
    int bm = blockIdx.x << 5, bn = by << 6;
    int wv = t >> 6, lane = t & 63;
    int mt = wv & 1, nt0 = (wv >> 1) << 1;
    int quad = lane >> 4, l16 = lane & 15;
    {
        int ar = t >> 3, cq = (t & 7) << 2;
        const float* ap = j.A + (size_t)(bm + ar) * 256 + cq;
#pragma unroll
        for (int g = 0; g < 8; ++g) {
            float4 v = *(const float4*)(ap + g * 32);
            short4v o;
            o[0] = (short)f2bf(v.x);
            o[1] = (short)f2bf(v.y);
            o[2] = (short)f2bf(v.z);
            o[3] = (short)f2bf(v.w);
            *(short4v*)&As[ar][cq + g * 32] = o;
        }
    }
    {
        int br = t >> 2, o = (t & 3) << 6;
        const unsigned short* bp = j.Bt + (size_t)(bn + br) * 256 + o;
#pragma unroll
        for (int c = 0; c < 8; ++c)
            *(uint4*)&Bs[br][o + (c << 3)] = *(const uint4*)(bp + (c << 3));
    }
    __syncthreads();
    floatx4 acc0 = {0.f, 0.f, 0.f, 0.f};
    floatx4 acc1 = {0.f, 0.f, 0.f, 0.f};
#pragma unroll
    for (int k0 = 0; k0 < 8; ++k0) {
        short8 aa = *(const short8*)&As[(mt << 4) + l16][(k0 << 5) + (quad << 3)];
        short8 b0 = *(const short8*)&Bs[(nt0 << 4) + l16][(k0 << 5) + (quad << 3)];
        short8 b1 =
            *(const short8*)&Bs[((nt0 + 1) << 4) + l16][(k0 << 5) + (quad << 3)];
        acc0 = __builtin_amdgcn_mfma_f32_16x16x32_bf16(aa, b0, acc0, 0, 0, 0);
        acc1 = __builtin_amdgcn_mfma_f32_16x16x32_bf16(aa, b1, acc1, 0, 0, 0);
    }
#pragma unroll
    for (int jj = 0; jj < 2; ++jj) {
        const floatx4 accv = jj ? acc1 : acc0;
        int col = bn + ((nt0 + jj) << 4) + l16;
        float bv = j.bias[col];
#pragma unroll
        for (int r = 0; r < 4; ++r) {
            int row = bm + (mt << 4) + (quad << 2) + r;
            float v = accv[r] + bv;
            if (col < 256)
                j.Kt[(size_t)row * 256 + col] = f2bf(v);
            else
                j.Vt[(size_t)(col - 256) * M_DIM + row] = f2bf(v);
        }
    }
}

// ======================= per-transformer-block megakernel ==================
// One block per 16-query bucket chunk. Whole chain in LDS:
// gather x -> LN(x) [LNM==2: LN->ln_post0 affine->LN] -> Q -> attention ->
// proj -> LN_pre -> m1+gelu -> m2 + residual -> scatter x'.
template <int LNM>
__global__ __launch_bounds__(256) void mega_kernel(
    const float* __restrict__ xin, float* __restrict__ xout,
    const unsigned short* __restrict__ Kt, const unsigned short* __restrict__ Vtab,
    const unsigned short* __restrict__ Wq, const unsigned short* __restrict__ Wp,
    const unsigned short* __restrict__ Wm1, const unsigned short* __restrict__ Wm2,
    const float* __restrict__ bq, const float* __restrict__ bp,
    const float* __restrict__ bm1f, const float* __restrict__ bm2,
    const float* __restrict__ rw, const float* __restrict__ rb,
    const float* __restrict__ aw, const float* __restrict__ ab,
    const int* __restrict__ perm, const int4* __restrict__ chunks,
    const int* __restrict__ nchunks) {
    __shared__ short Bs[64][264];    // generic B staging / K rows
    __shared__ short VsT[256][72];   // V transposed [c][n]
    __shared__ short Xs[16][264];    // x-hat, later z-hat (bf16)
    __shared__ short Qs[16][264];
    __shared__ short Os[16][264];    // attention output
    __shared__ float Zs[16][260];    // Z0 fp32, then z-hat fp32
    __shared__ short Hs[16][528];    // mlp hidden (bf16)
    __shared__ float Ss[16][68];
    __shared__ short Pb[16][72];
    __shared__ int gq[16];
    if ((int)blockIdx.x >= *nchunks) return;
    int4 cd = chunks[blockIdx.x];
    int wl = cd.x, q0 = cd.y, qcnt = cd.z;
    int t = threadIdx.x;
    int wv = t >> 6, lane = t & 63, quad = lane >> 4, l16 = lane & 15;
    if (t < 16) gq[t] = perm[q0 + min(t, qcnt - 1)];
    __syncthreads();
    // ---- 1: gather x rows + LN -> Xs bf16
    {
        int row = t >> 4, seg = t & 15;
        const float* xp = xin + (size_t)gq[row] * 256 + (seg << 4);
        float4 v[4];
#pragma unroll
        for (int c = 0; c < 4; ++c) v[c] = *(const float4*)(xp + (c << 2));
        float s = 0.f, ss = 0.f;
#pragma unroll
        for (int c = 0; c < 4; ++c) {
            s += v[c].x + v[c].y + v[c].z + v[c].w;
            ss += v[c].x * v[c].x + v[c].y * v[c].y + v[c].z * v[c].z +
                  v[c].w * v[c].w;
        }
#pragma unroll
        for (int o = 1; o < 16; o <<= 1) {
            s += __shfl_xor(s, o, 64);
            ss += __shfl_xor(ss, o, 64);
        }
        float mu = s * (1.f / 256.f);
        float rs = rsqrtf(ss * (1.f / 256.f) - mu * mu + 1e-5f);
#pragma unroll
        for (int c = 0; c < 4; ++c) {
            v[c].x = (v[c].x - mu) * rs;
            v[c].y = (v[c].y - mu) * rs;
            v[c].z = (v[c].z - mu) * rs;
            v[c].w = (v[c].w - mu) * rs;
        }
        if (LNM == 2) {
            float s2 = 0.f, ss2 = 0.f;
#pragma unroll
            for (int c = 0; c < 4; ++c) {
                float4 w4 = *(const float4*)&aw[(seg << 4) + (c << 2)];
                float4 b4 = *(const float4*)&ab[(seg << 4) + (c << 2)];
                v[c].x = v[c].x * w4.x + b4.x;
                v[c].y = v[c].y * w4.y + b4.y;
                v[c].z = v[c].z * w4.z + b4.z;
                v[c].w = v[c].w * w4.w + b4.w;
                s2 += v[c].x + v[c].y + v[c].z + v[c].w;
                ss2 += v[c].x * v[c].x + v[c].y * v[c].y + v[c].z * v[c].z +
                       v[c].w * v[c].w;
            }
#pragma unroll
            for (int o = 1; o < 16; o <<= 1) {
                s2 += __shfl_xor(s2, o, 64);
                ss2 += __shfl_xor(ss2, o, 64);
            }
            float mu2 = s2 * (1.f / 256.f);
            float rs2 = rsqrtf(ss2 * (1.f / 256.f) - mu2 * mu2 + 1e-5f);
#pragma unroll
            for (int c = 0; c < 4; ++c) {
                v[c].x = (v[c].x - mu2) * rs2;
                v[c].y = (v[c].y - mu2) * rs2;
                v[c].z = (v[c].z - mu2) * rs2;
                v[c].w = (v[c].w - mu2) * rs2;
            }
        }
#pragma unroll
        for (int c = 0; c < 4; ++c) {
            short4v o;
            o[0] = (short)f2bf(v[c].x);
            o[1] = (short)f2bf(v[c].y);
            o[2] = (short)f2bf(v[c].z);
            o[3] = (short)f2bf(v[c].w);
            *(short4v*)&Xs[row][(seg << 4) + (c << 2)] = o;
        }
    }
    __syncthreads();
    // ---- 2: Q = Xs @ Wq' + bq'  -> Qs bf16
#pragma unroll 1
    for (int nc = 0; nc < 4; ++nc) {
        {
            int br = t >> 2, o = (t & 3) << 6;
            const unsigned short* bp2 = Wq + (size_t)((nc << 6) + br) * 256 + o;
#pragma unroll
            for (int c = 0; c < 8; ++c)
                *(uint4*)&Bs[br][o + (c << 3)] = *(const uint4*)(bp2 + (c << 3));
        }
        __syncthreads();
        floatx4 acc = {0.f, 0.f, 0.f, 0.f};
#pragma unroll
        for (int k0 = 0; k0 < 8; ++k0) {
            short8 aa = *(const short8*)&Xs[l16][(k0 << 5) + (quad << 3)];
            short8 bb2 = *(const short8*)&Bs[(wv << 4) + l16][(k0 << 5) + (quad << 3)];
            acc = __builtin_amdgcn_mfma_f32_16x16x32_bf16(aa, bb2, acc, 0, 0, 0);
        }
        int nb = (nc << 6) + (wv << 4);
        float bv = bq[nb + l16];
#pragma unroll
        for (int r = 0; r < 4; ++r)
            Qs[(quad << 2) + r][nb + l16] = (short)f2bf(acc[r] + bv);
        __syncthreads();
    }
    // ---- 3: attention. Bs <- 64 K rows; VsT <- V cols.
    {
        int br = t >> 2, o = (t & 3) << 6;
        const unsigned short* kp = Kt + ((size_t)(wl << 5) + br) * 256 + o;
#pragma unroll
        for (int c = 0; c < 8; ++c)
            *(uint4*)&Bs[br][o + (c << 3)] = *(const uint4*)(kp + (c << 3));
        const unsigned short* vp = Vtab + (size_t)t * M_DIM + (wl << 5);
#pragma unroll
        for (int c = 0; c < 8; ++c)
            *(uint4*)&VsT[t][c << 3] = *(const uint4*)(vp + (c << 3));
    }
    __syncthreads();
#pragma unroll 1
    for (int h = 0; h < 8; ++h) {
        {
            short8 aa = *(const short8*)&Qs[l16][(h << 5) + (quad << 3)];
            short8 bb2 = *(const short8*)&Bs[(wv << 4) + l16][(h << 5) + (quad << 3)];
            floatx4 z = {0.f, 0.f, 0.f, 0.f};
            floatx4 c0 = __builtin_amdgcn_mfma_f32_16x16x32_bf16(aa, bb2, z, 0, 0, 0);
#pragma unroll
            for (int r = 0; r < 4; ++r)
                Ss[(quad << 2) + r][(wv << 4) + l16] = c0[r];
        }
        __syncthreads();
        {
            int row = t >> 4, seg = t & 15;
            float e[4];
            float s = 0.f;
#pragma unroll
            for (int c = 0; c < 4; ++c) {
                e[c] = __expf(Ss[row][(seg << 2) + c] * ATT_SCALE);
                s += e[c];
            }
#pragma unroll
            for (int o = 1; o < 16; o <<= 1) s += __shfl_xor(s, o, 64);
            float ri = 1.f / s;
#pragma unroll
            for (int c = 0; c < 4; ++c)
                Pb[row][(seg << 2) + c] = (short)f2bf(e[c] * ri);
        }
        __syncthreads();
        if (wv < 2) {
            floatx4 acc = {0.f, 0.f, 0.f, 0.f};
#pragma unroll
            for (int ks = 0; ks < 2; ++ks) {
                short8 aa = *(const short8*)&Pb[l16][(ks << 5) + (quad << 3)];
                short8 bb2 = *(const short8*)&VsT[(h << 5) + (wv << 4) + l16]
                                                 [(ks << 5) + (quad << 3)];
                acc = __builtin_amdgcn_mfma_f32_16x16x32_bf16(aa, bb2, acc, 0, 0, 0);
            }
#pragma unroll
            for (int r = 0; r < 4; ++r)
                Os[(quad << 2) + r][(h << 5) + (wv << 4) + l16] =
                    (short)f2bf(acc[r]);
        }
        __syncthreads();
    }
    // ---- 4: Z0 = Os @ Wproj + bproj -> Zs fp32
#pragma unroll 1
    for (int nc = 0; nc < 4; ++nc) {
        {
            int br = t >> 2, o = (t & 3) << 6;
            const unsigned short* bp2 = Wp + (size_t)((nc << 6) + br) * 256 + o;
#pragma unroll
            for (int c = 0; c < 8; ++c)
                *(uint4*)&Bs[br][o + (c << 3)] = *(const uint4*)(bp2 + (c << 3));
        }
        __syncthreads();
        floatx4 acc = {0.f, 0.f, 0.f, 0.f};
#pragma unroll
        for (int k0 = 0; k0 < 8; ++k0) {
            short8 aa = *(const short8*)&Os[l16][(k0 << 5) + (quad << 3)];
            short8 bb2 = *(const short8*)&Bs[(wv << 4) + l16][(k0 << 5) + (quad << 3)];
            acc = __builtin_amdgcn_mfma_f32_16x16x32_bf16(aa, bb2, acc, 0, 0, 0);
        }
        int nb = (nc << 6) + (wv << 4);
        float bv = bp[nb + l16];
#pragma unroll
        for (int r = 0; r < 4; ++r)
            Zs[(quad << 2) + r][nb + l16] = acc[r] + bv;
        __syncthreads();
    }
    // ---- 5: z-hat = LN(Z0): fp32 back to Zs, bf16 to Xs
    {
        int row = t >> 4, seg = t & 15;
        float4 v[4];
#pragma unroll
        for (int c = 0; c < 4; ++c)
            v[c] = *(const float4*)&Zs[row][(seg << 4) + (c << 2)];
        float s = 0.f, ss = 0.f;
#pragma unroll
        for (int c = 0; c < 4; ++c) {
            s += v[c].x + v[c].y + v[c].z + v[c].w;
            ss += v[c].x * v[c].x + v[c].y * v[c].y + v[c].z * v[c].z +
                  v[c].w * v[c].w;
        }
#pragma unroll
        for (int o = 1; o < 16; o <<= 1) {
            s += __shfl_xor(s, o, 64);
            ss += __shfl_xor(ss, o, 64);
        }
        float mu = s * (1.f / 256.f);
        float rs = rsqrtf(ss * (1.f / 256.f) - mu * mu + 1e-5f);
#pragma unroll
        for (int c = 0; c < 4; ++c) {
            v[c].x = (v[c].x - mu) * rs;
            v[c].y = (v[c].y - mu) * rs;
            v[c].z = (v[c].z - mu) * rs;
            v[c].w = (v[c].w - mu) * rs;
            *(float4*)&Zs[row][(seg << 4) + (c << 2)] = v[c];
            short4v o;
            o[0] = (short)f2bf(v[c].x);
            o[1] = (short)f2bf(v[c].y);
            o[2] = (short)f2bf(v[c].z);
            o[3] = (short)f2bf(v[c].w);
            *(short4v*)&Xs[row][(seg << 4) + (c << 2)] = o;
        }
    }
    __syncthreads();
    // ---- 6: H = gelu(z-hat @ Wm1' + bm1') -> Hs bf16
#pragma unroll 1
    for (int nc = 0; nc < 8; ++nc) {
        {
            int br = t >> 2, o = (t & 3) << 6;
            const unsigned short* bp2 = Wm1 + (size_t)((nc << 6) + br) * 256 + o;
#pragma unroll
            for (int c = 0; c < 8; ++c)
                *(uint4*)&Bs[br][o + (c << 3)] = *(const uint4*)(bp2 + (c << 3));
        }
        __syncthreads();
        floatx4 acc = {0.f, 0.f, 0.f, 0.f};
#pragma unroll
        for (int k0 = 0; k0 < 8; ++k0) {
            short8 aa = *(const short8*)&Xs[l16][(k0 << 5) + (quad << 3)];
            short8 bb2 = *(const short8*)&Bs[(wv << 4) + l16][(k0 << 5) + (quad << 3)];
            acc = __builtin_amdgcn_mfma_f32_16x16x32_bf16(aa, bb2, acc, 0, 0, 0);
        }
        int nb = (nc << 6) + (wv << 4);
        float bv = bm1f[nb + l16];
#pragma unroll
        for (int r = 0; r < 4; ++r)
            Hs[(quad << 2) + r][nb + l16] = (short)f2bf(gelu_exact(acc[r] + bv));
        __syncthreads();
    }
    // ---- 7: x' = z_affine + H @ Wm2 + bm2, scatter to xout
#pragma unroll 1
    for (int nc = 0; nc < 4; ++nc) {
        floatx4 acc = {0.f, 0.f, 0.f, 0.f};
#pragma unroll 1
        for (int kh = 0; kh < 2; ++kh) {
            {
                int br = t >> 2, o = (t & 3) << 6;
                const unsigned short* bp2 =
                    Wm2 + (size_t)((nc << 6) + br) * 512 + (kh << 8) + o;
#pragma unroll
                for (int c = 0; c < 8; ++c)
                    *(uint4*)&Bs[br][o + (c << 3)] = *(const uint4*)(bp2 + (c << 3));
            }
            __syncthreads();
#pragma unroll
            for (int k0 = 0; k0 < 8; ++k0) {
                short8 aa =
                    *(const short8*)&Hs[l16][(kh << 8) + (k0 << 5) + (quad << 3)];
                short8 bb2 =
                    *(const short8*)&Bs[(wv << 4) + l16][(k0 << 5) + (quad << 3)];
                acc = __builtin_amdgcn_mfma_f32_16x16x32_bf16(aa, bb2, acc, 0, 0, 0);
            }
            __syncthreads();
        }
        int nb = (nc << 6) + (wv << 4);
        int col = nb + l16;
        float bv = bm2[col], rwv = rw[col], rbv = rb[col];
#pragma unroll
        for (int r = 0; r < 4; ++r) {
            int row = (quad << 2) + r;
            if (row < qcnt)
                xout[(size_t)gq[row] * 256 + col] =
                    acc[r] + bv + Zs[row][col] * rwv + rbv;
        }
    }
}

// ======================= final: LN_post + L2 norm + transpose ==============
__global__ __launch_bounds__(256) void out_kernel(const float* __restrict__ X,
                                                  const float* __restrict__ w,
                                                  const float* __restrict__ b,
                                                  float* __restrict__ out) {
    __shared__ float tile[64][65];
    int t = threadIdx.x;
    int mo = t >> 2, q = t & 3;
    int m0 = blockIdx.x << 6;
    const float* p = X + (size_t)(m0 + mo) * C_DIM + (q << 6);
    float4 v[16];
    float s = 0.f, ss = 0.f;
#pragma unroll
    for (int c = 0; c < 16; ++c) {
        v[c] = *(const float4*)(p + c * 4);
        s += v[c].x + v[c].y + v[c].z + v[c].w;
        ss += v[c].x * v[c].x + v[c].y * v[c].y + v[c].z * v[c].z + v[c].w * v[c].w;
    }
    s += __shfl_xor(s, 1, 64); s += __shfl_xor(s, 2, 64);
    ss += __shfl_xor(ss, 1, 64); ss += __shfl_xor(ss, 2, 64);
    float mu = s * (1.f / 256.f);
    float rs = rsqrtf(ss * (1.f / 256.f) - mu * mu + 1e-5f);
    float ss2 = 0.f;
#pragma unroll
    for (int c = 0; c < 16; ++c) {
        float4 w4 = *(const float4*)&w[(q << 6) + c * 4];
        float4 b4 = *(const float4*)&b[(q << 6) + c * 4];
        v[c].x = (v[c].x - mu) * rs * w4.x + b4.x;
        v[c].y = (v[c].y - mu) * rs * w4.y + b4.y;
        v[c].z = (v[c].z - mu) * rs * w4.z + b4.z;
        v[c].w = (v[c].w - mu) * rs * w4.w + b4.w;
        ss2 += v[c].x * v[c].x + v[c].y * v[c].y + v[c].z * v[c].z + v[c].w * v[c].w;
    }
    ss2 += __shfl_xor(ss2, 1, 64); ss2 += __shfl_xor(ss2, 2, 64);
    float sc = 1.f / fmaxf(sqrtf(ss2), 1e-12f);
    for (int cc = 0; cc < 4; ++cc) {
        if (q == cc) {
#pragma unroll
            for (int c = 0; c < 16; ++c) {
                tile[mo][c * 4 + 0] = v[c].x * sc;
                tile[mo][c * 4 + 1] = v[c].y * sc;
                tile[mo][c * 4 + 2] = v[c].z * sc;
                tile[mo][c * 4 + 3] = v[c].w * sc;
            }
        }
        __syncthreads();
        for (int it = 0; it < 16; ++it) {
            int idx = it * 256 + t;
            int co = idx >> 6, mr = idx & 63;
            out[(size_t)((cc << 6) + co) * M_DIM + m0 + mr] = tile[mr][co];
        }
        __syncthreads();
    }
}

// ---------------------------------------------------------------------------
extern "C" void kernel_launch(void* const* d_in, const int* in_sizes, int n_in,
                              void* d_out, int out_size, void* d_ws, size_t ws_size,
                              hipStream_t stream) {
    const float* grd2sat = (const float*)d_in[0];
    const float* grd_x   = (const float*)d_in[1];
    const float* u       = (const float*)d_in[2];
    const float* ln_q_w  = (const float*)d_in[3];
    const float* ln_q_b  = (const float*)d_in[4];
    const float* ln_k_w  = (const float*)d_in[5];
    const float* ln_k_b  = (const float*)d_in[6];
    const float* ln_v_w  = (const float*)d_in[7];
    const float* ln_v_b  = (const float*)d_in[8];
    const float* Wq      = (const float*)d_in[9];
    const float* Wk      = (const float*)d_in[10];
    const float* Wv      = (const float*)d_in[11];
    const float* Wproj   = (const float*)d_in[12];
    const float* bproj   = (const float*)d_in[13];
    const float* ln_pre_w = (const float*)d_in[14];
    const float* ln_pre_b = (const float*)d_in[15];
    const float* Wm1     = (const float*)d_in[16];
    const float* bm1     = (const float*)d_in[17];
    const float* Wm2     = (const float*)d_in[18];
    const float* bm2     = (const float*)d_in[19];
    const float* ln_post_w = (const float*)d_in[20];
    const float* ln_post_b = (const float*)d_in[21];

    float* ws   = (float*)d_ws;
    float* yhat = ws;                    // 4 MB
    float* xcur = ws + 1048576;          // 4 MB
    float* xb1  = ws + 2097152;          // 4 MB
    float* xb2  = ws + 3145728;          // 4 MB
    unsigned short* Ktab0 = (unsigned short*)(ws + 4194304);  // 2 MB
    unsigned short* Vt0   = (unsigned short*)(ws + 4718592);  // 2 MB
    unsigned short* Ktab1 = (unsigned short*)(ws + 5242880);  // 2 MB
    unsigned short* Vt1   = (unsigned short*)(ws + 5767168);  // 2 MB
    unsigned short* Bt    = (unsigned short*)(ws + 6291456);  // 2 MB (both blocks)
    float* biasbuf = ws + 6815744;       // 2560 floats
    int*  perm    = (int*)(ws + 6818304);
    int4* chunks  = (int4*)(ws + 6822400);   // 512 int4
    int*  nchunks = (int*)(ws + 6824448);
    const size_t BS = 524288;
    const size_t OQ = 0, OKV = 65536, OP = 196608, OM1 = 262144, OM2 = 393216;

    dim3 b256(256);

    PrepArgs pa;
    pa.grd2sat = grd2sat; pa.xcur = xcur;
    pa.grd_x = grd_x;     pa.yhat = yhat;
    pa.u = u; pa.perm = perm; pa.chunks = chunks; pa.nchunks = nchunks;
    {
        int base = 0;
        for (int i = 0; i < 2; ++i) {
            int e = 6 * i;
            unsigned short* bt = Bt + i * BS;
            pa.win[e+0] = Wq + i * 65536;    pa.wout[e+0] = bt + OQ;
            pa.wlnw[e+0] = ln_q_w + i * 256; pa.wR[e+0] = 256; pa.wC[e+0] = 256;
            pa.win[e+1] = Wk + i * 65536;    pa.wout[e+1] = bt + OKV;
            pa.wlnw[e+1] = ln_k_w + i * 256; pa.wR[e+1] = 256; pa.wC[e+1] = 256;
            pa.win[e+2] = Wv + i * 65536;    pa.wout[e+2] = bt + OKV + 65536;
            pa.wlnw[e+2] = ln_v_w + i * 256; pa.wR[e+2] = 256; pa.wC[e+2] = 256;
            pa.win[e+3] = Wproj + i * 65536; pa.wout[e+3] = bt + OP;
            pa.wlnw[e+3] = nullptr;          pa.wR[e+3] = 256; pa.wC[e+3] = 256;
            pa.win[e+4] = Wm1 + i * 131072;  pa.wout[e+4] = bt + OM1;
            pa.wlnw[e+4] = ln_pre_w + i * 256; pa.wR[e+4] = 256; pa.wC[e+4] = 512;
            pa.win[e+5] = Wm2 + i * 131072;  pa.wout[e+5] = bt + OM2;
            pa.wlnw[e+5] = nullptr;          pa.wR[e+5] = 512; pa.wC[e+5] = 256;
        }
        for (int e = 0; e < 12; ++e) {
            pa.wbase[e] = base;
            base += (pa.wR[e] >> 5) * (pa.wC[e] >> 5);
        }
        pa.wbase[12] = base;  // 1024
        for (int i = 0; i < 2; ++i) {
            int jb = 5 * i;
            float* bb = biasbuf + i * 1280;
            pa.fW[jb+0] = Wq + i * 65536; pa.flnb[jb+0] = ln_q_b + i * 256;
            pa.fbase[jb+0] = nullptr; pa.fout[jb+0] = bb;
            pa.fN[jb+0] = 256; pa.fwcol[jb+0] = 0; pa.focol[jb+0] = 0;
            pa.fW[jb+1] = Wk + i * 65536; pa.flnb[jb+1] = ln_k_b + i * 256;
            pa.fbase[jb+1] = nullptr; pa.fout[jb+1] = bb + 256;
            pa.fN[jb+1] = 256; pa.fwcol[jb+1] = 0; pa.focol[jb+1] = 0;
            pa.fW[jb+2] = Wv + i * 65536; pa.flnb[jb+2] = ln_v_b + i * 256;
            pa.fbase[jb+2] = nullptr; pa.fout[jb+2] = bb + 256;
            pa.fN[jb+2] = 256; pa.fwcol[jb+2] = 0; pa.focol[jb+2] = 256;
            pa.fW[jb+3] = Wm1 + i * 131072; pa.flnb[jb+3] = ln_pre_b + i * 256;
            pa.fbase[jb+3] = bm1 + i * 512; pa.fout[jb+3] = bb + 768;
            pa.fN[jb+3] = 512; pa.fwcol[jb+3] = 0; pa.focol[jb+3] = 0;
            pa.fW[jb+4] = Wm1 + i * 131072; pa.flnb[jb+4] = ln_pre_b + i * 256;
            pa.fbase[jb+4] = bm1 + i * 512; pa.fout[jb+4] = bb + 768;
            pa.fN[jb+4] = 512; pa.fwcol[jb+4] = 256; pa.focol[jb+4] = 256;
        }
    }
    prep_kernel<<<1419, b256, 0, stream>>>(pa);

    KVJob k0 = {yhat, Bt + OKV, biasbuf + 256, Ktab0, Vt0};
    KVJob k1 = {yhat, Bt + BS + OKV, biasbuf + 1280 + 256, Ktab1, Vt1};
    kv_gemm<<<dim3(128, 16), b256, 0, stream>>>(k0, k1);

    mega_kernel<1><<<384, b256, 0, stream>>>(
        xcur, xb1, Ktab0, Vt0, Bt + OQ, Bt + OP, Bt + OM1, Bt + OM2,
        biasbuf, bproj, biasbuf + 768, bm2, ln_pre_w, ln_pre_b,
        nullptr, nullptr, perm, chunks, nchunks);
    mega_kernel<2><<<384, b256, 0, stream>>>(
        xb1, xb2, Ktab1, Vt1, Bt + BS + OQ, Bt + BS + OP, Bt + BS + OM1,
        Bt + BS + OM2, biasbuf + 1280, bproj + 256, biasbuf + 1280 + 768,
        bm2 + 256, ln_pre_w + 256, ln_pre_b + 256, ln_post_w, ln_post_b,
        perm, chunks, nchunks);

    out_kernel<<<64, b256, 0, stream>>>(xb2, ln_post_w + 256, ln_post_b + 256,
                                        (float*)d_out);
}

// Round 6
// 231.962 us; speedup vs baseline: 1.4921x; 1.4921x over previous
//
#include <hip/hip_runtime.h>
#include <math.h>

// ---------------------------------------------------------------------------
// CrossViewAttention — R4 structure + proj fused into bucketed attention.
// B=1, C=256, M=4096, W=128, H=32, BLOCKS=2, HEADS=8, DH=32
// ---------------------------------------------------------------------------

#define C_DIM 256
#define M_DIM 4096
#define W_DIM 128
#define H_DIM 32
#define ATT_SCALE 0.17677669529663687f  // 1/sqrt(32)

typedef __attribute__((ext_vector_type(8))) short short8;
typedef __attribute__((ext_vector_type(4))) short short4v;
typedef __attribute__((ext_vector_type(4))) float floatx4;

__device__ __forceinline__ unsigned short f2bf(float f) {
    unsigned u = __float_as_uint(f);
    unsigned r = (u + 0x7fffu + ((u >> 16) & 1u)) >> 16;
    return (unsigned short)r;
}
__device__ __forceinline__ float gelu_exact(float x) {
    return 0.5f * x * (1.0f + erff(x * 0.70710678118654752f));
}

// ======================= mega prep kernel ==================================
// roles by blockIdx.x:
//   [0,256)    transpose grd2sat (C,M) -> xcur (M,C)
//   [256,384)  yhat: LN over C of grd_x columns -> yhat[(w*32+h)][c]
//   [384,1408) weight transpose+scale+convert: W'[n][k] = ln_w[k]*W[k][n] bf16
//   [1408,1418) folded biases: out[col] = base[col] + sum_k ln_b[k]*W[k][col]
//   1418       bucket sort of queries by wl=floor(u): perm/chunks/nchunks
struct PrepArgs {
    const float* grd2sat; float* xcur;
    const float* grd_x;   float* yhat;
    const float* u; int* perm; int4* chunks; int* nchunks;
    const float* win[12]; unsigned short* wout[12]; const float* wlnw[12];
    int wR[12], wC[12], wbase[13];
    const float* fW[10]; const float* flnb[10]; const float* fbase[10];
    float* fout[10];
    int fN[10], fwcol[10], focol[10];
};

__global__ __launch_bounds__(256) void prep_kernel(PrepArgs a) {
    __shared__ float smemf[9024];
    int b = blockIdx.x, t = threadIdx.x;
    if (b < 256) {
        float (*tile)[65] = (float(*)[65])smemf;
        int m0 = (b & 63) << 6, c0 = (b >> 6) << 6;
        for (int it = 0; it < 16; ++it) {
            int idx = it * 256 + t;
            int co = idx >> 6, mo = idx & 63;
            tile[co][mo] = a.grd2sat[(size_t)(c0 + co) * M_DIM + m0 + mo];
        }
        __syncthreads();
        for (int it = 0; it < 16; ++it) {
            int idx = it * 256 + t;
            int mo = idx >> 6, co = idx & 63;
            a.xcur[(size_t)(m0 + mo) * C_DIM + c0 + co] = tile[co][mo];
        }
    } else if (b < 384) {
        int idx = b - 256;
        int h = idx & 31, w0 = (idx >> 5) << 5;
        float (*tile)[33] = (float(*)[33])smemf;
        float (*ps)[32] = (float(*)[32])(smemf + 8448);
        float (*pss)[32] = (float(*)[32])(smemf + 8704);
        float* mu_s = smemf + 8960;
        float* rs_s = smemf + 8992;
        int wo = t & 31, cb = t >> 5;
        for (int it = 0; it < 32; ++it) {
            int c = it * 8 + cb;
            tile[c][wo] = a.grd_x[(size_t)c * (H_DIM * W_DIM) + h * W_DIM + w0 + wo];
        }
        __syncthreads();
        {
            int w = t & 31, part = t >> 5;
            float s = 0.f, ss = 0.f;
            for (int c = part * 32; c < part * 32 + 32; ++c) {
                float x = tile[c][w];
                s += x; ss += x * x;
            }
            ps[part][w] = s; pss[part][w] = ss;
        }
        __syncthreads();
        if (t < 32) {
            float s = 0.f, ss = 0.f;
            for (int p = 0; p < 8; ++p) { s += ps[p][t]; ss += pss[p][t]; }
            float mu = s * (1.f / 256.f);
            float var = ss * (1.f / 256.f) - mu * mu;
            mu_s[t] = mu;
            rs_s[t] = rsqrtf(var + 1e-5f);
        }
        __syncthreads();
        for (int jj = 0; jj < 32; ++jj) {
            float mu = mu_s[jj], rs = rs_s[jj];
            a.yhat[((size_t)(w0 + jj) * H_DIM + h) * C_DIM + t] =
                (tile[t][jj] - mu) * rs;
        }
    } else if (b < 1408) {
        int wI = b - 384;
        int e = 0;
        while (wI >= a.wbase[e + 1]) ++e;
        int tl = wI - a.wbase[e];
        int tilesC = a.wC[e] >> 5;
        int tr = tl / tilesC, tc = tl - tr * tilesC;
        int r0 = tr << 5, c0 = tc << 5;
        const float* in = a.win[e];
        unsigned short* out = a.wout[e];
        const float* lnw = a.wlnw[e];
        int R = a.wR[e], Cc = a.wC[e];
        float (*tile)[33] = (float(*)[33])smemf;
        int rl = t >> 3, cq = (t & 7) << 2;
        float4 v = *(const float4*)&in[(size_t)(r0 + rl) * Cc + c0 + cq];
        if (lnw) {
            float s = lnw[r0 + rl];
            v.x *= s; v.y *= s; v.z *= s; v.w *= s;
        }
        tile[rl][cq + 0] = v.x;
        tile[rl][cq + 1] = v.y;
        tile[rl][cq + 2] = v.z;
        tile[rl][cq + 3] = v.w;
        __syncthreads();
        int cl = t >> 3, rq = (t & 7) << 2;
        ushort4 o;
        o.x = f2bf(tile[rq + 0][cl]);
        o.y = f2bf(tile[rq + 1][cl]);
        o.z = f2bf(tile[rq + 2][cl]);
        o.w = f2bf(tile[rq + 3][cl]);
        *(ushort4*)&out[(size_t)(c0 + cl) * R + r0 + rq] = o;
    } else if (b < 1418) {
        int jj = b - 1408;
        int N = a.fN[jj];
        int wcol = a.fwcol[jj] + t;
        const float* W = a.fW[jj];
        const float* lb = a.flnb[jj];
        float s = a.fbase[jj] ? a.fbase[jj][wcol] : 0.f;
        for (int k = 0; k < 256; ++k) s += lb[k] * W[(size_t)k * N + wcol];
        a.fout[jj][a.focol[jj] + t] = s;
    } else {
        // ---- bucket sort by wl = floor(u[m]) in [0,126]
        int* hist = (int*)smemf;
        int* cur = (int*)smemf + 128;
        unsigned short* wlb = (unsigned short*)((int*)smemf + 256);
        if (t < 128) hist[t] = 0;
        __syncthreads();
        for (int it = 0; it < 16; ++it) {
            int m = it * 256 + t;
            int wl = (int)floorf(a.u[m]);
            wl = max(0, min(wl, 126));
            wlb[m] = (unsigned short)wl;
            atomicAdd(&hist[wl], 1);
        }
        __syncthreads();
        if (t == 0) {
            int run = 0, nc = 0;
            for (int bkt = 0; bkt < 127; ++bkt) {
                int c = hist[bkt];
                cur[bkt] = run;
                int q0 = run;
                while (c > 0) {
                    int take = min(c, 32);
                    a.chunks[nc] = make_int4(bkt, q0, take, 0);
                    ++nc; q0 += take; c -= take;
                }
                run += hist[bkt];
            }
            *a.nchunks = nc;
        }
        __syncthreads();
        for (int it = 0; it < 16; ++it) {
            int m = it * 256 + t;
            int wl = wlb[m];
            int pos = atomicAdd(&cur[wl], 1);
            a.perm[pos] = m;
        }
    }
}

// ======================= templated MFMA GEMM ===============================
// BM=32, BN=64, 256 threads. A fp32 [M][K]; Bt bf16 [N][K].
// LN: 0 none; 1 plain row-LN; 2 LN->affine(aw,ab)->LN.
// EPI: 0 bias; 1 bias+gelu; 2 bias + res*rw+rb.
// OUTM: 0 fp32 [M][N]; 1 bf16 [M][256]; 2 split col<256 -> bf16 [M][256],
//       col>=256 -> out2 bf16 [(col-256)][4096].
struct GJ {
    const float* A; const unsigned short* Bt;
    const float* bias; const float* aw; const float* ab;
    const float* rw; const float* rb; const float* res;
    float* wrz; void* out; unsigned short* out2;
    int K, N;
};

template <int LN, int EPI, int OUTM, bool WRZ>
__device__ __forceinline__ void gemm_core(const GJ& j, short (*As)[264],
                                          short (*Bs)[264], int bm, int by) {
    int t = threadIdx.x;
    int bn = by << 6;
    int wv = t >> 6, lane = t & 63;
    int mt = wv & 1, nt0 = (wv >> 1) << 1;
    int quad = lane >> 4, l16 = lane & 15;
    floatx4 acc0 = {0.f, 0.f, 0.f, 0.f};
    floatx4 acc1 = {0.f, 0.f, 0.f, 0.f};
    const int K = j.K;
    for (int kc = 0; kc < K; kc += 256) {
        if (kc) __syncthreads();
        {
            int ar = t >> 3, cq = (t & 7) << 2;
            const float* ap = j.A + (size_t)(bm + ar) * K + kc + cq;
            float4 v[8];
#pragma unroll
            for (int g = 0; g < 8; ++g) v[g] = *(const float4*)(ap + g * 32);
            if (LN >= 1) {
                float s = 0.f, ss = 0.f;
#pragma unroll
                for (int g = 0; g < 8; ++g) {
                    s += v[g].x + v[g].y + v[g].z + v[g].w;
                    ss += v[g].x * v[g].x + v[g].y * v[g].y + v[g].z * v[g].z +
                          v[g].w * v[g].w;
                }
#pragma unroll
                for (int o = 1; o < 8; o <<= 1) {
                    s += __shfl_xor(s, o, 64);
                    ss += __shfl_xor(ss, o, 64);
                }
                float mu = s * (1.f / 256.f);
                float rs = rsqrtf(ss * (1.f / 256.f) - mu * mu + 1e-5f);
#pragma unroll
                for (int g = 0; g < 8; ++g) {
                    v[g].x = (v[g].x - mu) * rs;
                    v[g].y = (v[g].y - mu) * rs;
                    v[g].z = (v[g].z - mu) * rs;
                    v[g].w = (v[g].w - mu) * rs;
                }
                if (LN == 2) {
                    float s2 = 0.f, ss2 = 0.f;
#pragma unroll
                    for (int g = 0; g < 8; ++g) {
                        float4 w4 = *(const float4*)(j.aw + cq + g * 32);
                        float4 b4 = *(const float4*)(j.ab + cq + g * 32);
                        v[g].x = v[g].x * w4.x + b4.x;
                        v[g].y = v[g].y * w4.y + b4.y;
                        v[g].z = v[g].z * w4.z + b4.z;
                        v[g].w = v[g].w * w4.w + b4.w;
                        s2 += v[g].x + v[g].y + v[g].z + v[g].w;
                        ss2 += v[g].x * v[g].x + v[g].y * v[g].y +
                               v[g].z * v[g].z + v[g].w * v[g].w;
                    }
#pragma unroll
                    for (int o = 1; o < 8; o <<= 1) {
                        s2 += __shfl_xor(s2, o, 64);
                        ss2 += __shfl_xor(ss2, o, 64);
                    }
                    float mu2 = s2 * (1.f / 256.f);
                    float rs2 = rsqrtf(ss2 * (1.f / 256.f) - mu2 * mu2 + 1e-5f);
#pragma unroll
                    for (int g = 0; g < 8; ++g) {
                        v[g].x = (v[g].x - mu2) * rs2;
                        v[g].y = (v[g].y - mu2) * rs2;
                        v[g].z = (v[g].z - mu2) * rs2;
                        v[g].w = (v[g].w - mu2) * rs2;
                    }
                }
            }
            if (WRZ) {
                if (by == 0) {
#pragma unroll
                    for (int g = 0; g < 8; ++g)
                        *(float4*)&j.wrz[(size_t)(bm + ar) * 256 + cq + g * 32] =
                            v[g];
                }
            }
#pragma unroll
            for (int g = 0; g < 8; ++g) {
                short4v o;
                o[0] = (short)f2bf(v[g].x);
                o[1] = (short)f2bf(v[g].y);
                o[2] = (short)f2bf(v[g].z);
                o[3] = (short)f2bf(v[g].w);
                *(short4v*)&As[ar][cq + g * 32] = o;
            }
        }
        {
            int br = t >> 2, cq2 = (t & 3) << 3;
            const unsigned short* bp = j.Bt + (size_t)(bn + br) * K + kc + cq2;
#pragma unroll
            for (int g = 0; g < 8; ++g)
                *(short8*)&Bs[br][cq2 + g * 32] = *(const short8*)(bp + g * 32);
        }
        __syncthreads();
#pragma unroll
        for (int k0 = 0; k0 < 8; ++k0) {
            short8 aa = *(const short8*)&As[(mt << 4) + l16][(k0 << 5) + (quad << 3)];
            short8 b0 = *(const short8*)&Bs[(nt0 << 4) + l16][(k0 << 5) + (quad << 3)];
            short8 b1 =
                *(const short8*)&Bs[((nt0 + 1) << 4) + l16][(k0 << 5) + (quad << 3)];
            acc0 = __builtin_amdgcn_mfma_f32_16x16x32_bf16(aa, b0, acc0, 0, 0, 0);
            acc1 = __builtin_amdgcn_mfma_f32_16x16x32_bf16(aa, b1, acc1, 0, 0, 0);
        }
    }
#pragma unroll
    for (int jj = 0; jj < 2; ++jj) {
        const floatx4 accv = jj ? acc1 : acc0;
        int col = bn + ((nt0 + jj) << 4) + l16;
        float bv = j.bias ? j.bias[col] : 0.f;
#pragma unroll
        for (int r = 0; r < 4; ++r) {
            int row = bm + (mt << 4) + (quad << 2) + r;
            float v = accv[r] + bv;
            if (EPI == 1) v = gelu_exact(v);
            if (EPI == 2)
                v += j.res[(size_t)row * 256 + col] * j.rw[col] + j.rb[col];
            if (OUTM == 0) {
                ((float*)j.out)[(size_t)row * j.N + col] = v;
            } else if (OUTM == 1) {
                ((unsigned short*)j.out)[(size_t)row * 256 + col] = f2bf(v);
            } else {
                if (col < 256)
                    ((unsigned short*)j.out)[(size_t)row * 256 + col] = f2bf(v);
                else
                    j.out2[(size_t)(col - 256) * M_DIM + row] = f2bf(v);
            }
        }
    }
}

// MODE 0: Q(i=0,LN=1,bf16-out) + KV split | MODE 1: Q(i=1,LN=2) + KV split
// MODE 3: m1 (LN+gelu+wrz) | MODE 4: m2 (residual epi)
template <int MODE>
__global__ __launch_bounds__(256) void gemm_mode(GJ j0, GJ j1) {
    __shared__ short As[32][264];
    __shared__ short Bs[64][264];
    int bm = blockIdx.x << 5;
    if (MODE == 0) {
        if ((int)blockIdx.y < 4) gemm_core<1, 0, 1, false>(j0, As, Bs, bm, blockIdx.y);
        else gemm_core<0, 0, 2, false>(j1, As, Bs, bm, blockIdx.y - 4);
    } else if (MODE == 1) {
        if ((int)blockIdx.y < 4) gemm_core<2, 0, 1, false>(j0, As, Bs, bm, blockIdx.y);
        else gemm_core<0, 0, 2, false>(j1, As, Bs, bm, blockIdx.y - 4);
    } else if (MODE == 3) {
        gemm_core<1, 1, 0, true>(j0, As, Bs, bm, blockIdx.y);
    } else {
        gemm_core<0, 2, 0, false>(j0, As, Bs, bm, blockIdx.y);
    }
}

// ======================= bucketed MFMA attention + fused proj ==============
// One block per (bucket, <=32-query chunk). K/V staged in LDS once; QK^T and
// PV via MFMA (P through LDS); then Z0 = O @ Wproj + bproj written fp32.
__global__ __launch_bounds__(256) void attn_proj_kernel(
    const unsigned short* __restrict__ Qb, const unsigned short* __restrict__ Kt,
    const unsigned short* __restrict__ Vt, const unsigned short* __restrict__ Wp,
    const float* __restrict__ bp, const int* __restrict__ perm,
    const int4* __restrict__ chunks, const int* __restrict__ nchunks,
    float* __restrict__ Zo) {
    __shared__ short Qs[32][264];
    __shared__ short Ks[64][264];   // K rows, then Wproj chunks
    __shared__ short VsT[256][72];
    __shared__ short Os[32][264];   // attention output (bf16)
    __shared__ float S[32][69];
    __shared__ short Pb[32][72];
    __shared__ int gperm[32];
    if ((int)blockIdx.x >= *nchunks) return;
    int4 cd = chunks[blockIdx.x];
    int wl = cd.x, qstart = cd.y, qcnt = cd.z;
    int t = threadIdx.x;
    if (t < 32) gperm[t] = (t < qcnt) ? perm[qstart + t] : 0;
    {   // Qs: 32 rows x 256 bf16, gathered by perm
        int q = t >> 3, p = t & 7;
        if (q < qcnt) {
            const uint4* src =
                (const uint4*)(Qb + (size_t)perm[qstart + q] * 256 + (p << 5));
#pragma unroll
            for (int c = 0; c < 4; ++c) *(uint4*)&Qs[q][(p << 5) + (c << 3)] = src[c];
        } else {
            uint4 z = make_uint4(0, 0, 0, 0);
#pragma unroll
            for (int c = 0; c < 4; ++c) *(uint4*)&Qs[q][(p << 5) + (c << 3)] = z;
        }
    }
    {   // Ks: 64 rows (wl*32 .. wl*32+63) x 256 bf16
        int n = t >> 2, p = t & 3;
        const uint4* src = (const uint4*)(Kt + ((size_t)(wl * 32 + n)) * 256 + (p << 6));
#pragma unroll
        for (int c = 0; c < 8; ++c) *(uint4*)&Ks[n][(p << 6) + (c << 3)] = src[c];
    }
    {   // VsT: 256 c-rows x 64 n
        const uint4* src = (const uint4*)(Vt + (size_t)t * M_DIM + (wl << 5));
#pragma unroll
        for (int c = 0; c < 8; ++c) *(uint4*)&VsT[t][c << 3] = *(const uint4*)&src[c];
    }
    __syncthreads();
    int wv = t >> 6, lane = t & 63, quad = lane >> 4, l16 = lane & 15;
    int mt = wv & 1, nt0 = (wv >> 1) << 1;
    int ntP = wv >> 1;
    int sq = t >> 3, sg = t & 7;
#pragma unroll 1
    for (int h = 0; h < 8; ++h) {
        {   // scores: S[32 q][64 n] for head h
            short8 aa = *(const short8*)&Qs[(mt << 4) + l16][(h << 5) + (quad << 3)];
            short8 b0 = *(const short8*)&Ks[(nt0 << 4) + l16][(h << 5) + (quad << 3)];
            short8 b1 =
                *(const short8*)&Ks[((nt0 + 1) << 4) + l16][(h << 5) + (quad << 3)];
            floatx4 z = {0.f, 0.f, 0.f, 0.f};
            floatx4 c0 = __builtin_amdgcn_mfma_f32_16x16x32_bf16(aa, b0, z, 0, 0, 0);
            floatx4 c1 = __builtin_amdgcn_mfma_f32_16x16x32_bf16(aa, b1, z, 0, 0, 0);
#pragma unroll
            for (int r = 0; r < 4; ++r) {
                int row = (mt << 4) + (quad << 2) + r;
                S[row][(nt0 << 4) + l16] = c0[r];
                S[row][((nt0 + 1) << 4) + l16] = c1[r];
            }
        }
        __syncthreads();
        {   // softmax row sq over 64 cols; normalized bf16 P
            float e[8];
            float s = 0.f;
#pragma unroll
            for (int c = 0; c < 8; ++c) {
                e[c] = __expf(S[sq][(sg << 3) + c] * ATT_SCALE);
                s += e[c];
            }
            s += __shfl_xor(s, 1, 64);
            s += __shfl_xor(s, 2, 64);
            s += __shfl_xor(s, 4, 64);
            float ri = 1.f / s;
#pragma unroll
            for (int c = 0; c < 8; ++c)
                Pb[sq][(sg << 3) + c] = (short)f2bf(e[c] * ri);
        }
        __syncthreads();
        {   // PV: O[32 q][32 d] for head h -> Os bf16
            floatx4 acc = {0.f, 0.f, 0.f, 0.f};
#pragma unroll
            for (int ks = 0; ks < 2; ++ks) {
                short8 aa =
                    *(const short8*)&Pb[(mt << 4) + l16][(ks << 5) + (quad << 3)];
                short8 bb = *(const short8*)&VsT[(h << 5) + (ntP << 4) + l16]
                                                [(ks << 5) + (quad << 3)];
                acc = __builtin_amdgcn_mfma_f32_16x16x32_bf16(aa, bb, acc, 0, 0, 0);
            }
#pragma unroll
            for (int r = 0; r < 4; ++r)
                Os[(mt << 4) + (quad << 2) + r][(h << 5) + (ntP << 4) + l16] =
                    (short)f2bf(acc[r]);
        }
        __syncthreads();
    }
    // ---- fused proj: Z0 = Os @ Wp' + bp -> Zo fp32 (scatter by gperm)
#pragma unroll 1
    for (int nc = 0; nc < 4; ++nc) {
        {   // stage Wp rows (nc*64..+64) x 256 into Ks
            int br = t >> 2, o = (t & 3) << 6;
            const unsigned short* wp2 = Wp + (size_t)((nc << 6) + br) * 256 + o;
#pragma unroll
            for (int c = 0; c < 8; ++c)
                *(uint4*)&Ks[br][o + (c << 3)] = *(const uint4*)(wp2 + (c << 3));
        }
        __syncthreads();
        floatx4 acc0 = {0.f, 0.f, 0.f, 0.f};
        floatx4 acc1 = {0.f, 0.f, 0.f, 0.f};
#pragma unroll
        for (int k0 = 0; k0 < 8; ++k0) {
            short8 aa = *(const short8*)&Os[(mt << 4) + l16][(k0 << 5) + (quad << 3)];
            short8 b0 = *(const short8*)&Ks[(nt0 << 4) + l16][(k0 << 5) + (quad << 3)];
            short8 b1 =
                *(const short8*)&Ks[((nt0 + 1) << 4) + l16][(k0 << 5) + (quad << 3)];
            acc0 = __builtin_amdgcn_mfma_f32_16x16x32_bf16(aa, b0, acc0, 0, 0, 0);
            acc1 = __builtin_amdgcn_mfma_f32_16x16x32_bf16(aa, b1, acc1, 0, 0, 0);
        }
#pragma unroll
        for (int jj = 0; jj < 2; ++jj) {
            const floatx4 av = jj ? acc1 : acc0;
            int col = (nc << 6) + ((nt0 + jj) << 4) + l16;
            float bv = bp[col];
#pragma unroll
            for (int r = 0; r < 4; ++r) {
                int q = (mt << 4) + (quad << 2) + r;
                if (q < qcnt)
                    Zo[(size_t)gperm[q] * C_DIM + col] = av[r] + bv;
            }
        }
        __syncthreads();
    }
}

// ======================= final: LN_post + L2 norm + transpose ==============
__global__ __launch_bounds__(256) void out_kernel(const float* __restrict__ X,
                                                  const float* __restrict__ w,
                                                  const float* __restrict__ b,
                                                  float* __restrict__ out) {
    __shared__ float tile[64][65];
    int t = threadIdx.x;
    int mo = t >> 2, q = t & 3;
    int m0 = blockIdx.x << 6;
    const float* p = X + (size_t)(m0 + mo) * C_DIM + (q << 6);
    float4 v[16];
    float s = 0.f, ss = 0.f;
#pragma unroll
    for (int c = 0; c < 16; ++c) {
        v[c] = *(const float4*)(p + c * 4);
        s += v[c].x + v[c].y + v[c].z + v[c].w;
        ss += v[c].x * v[c].x + v[c].y * v[c].y + v[c].z * v[c].z + v[c].w * v[c].w;
    }
    s += __shfl_xor(s, 1, 64); s += __shfl_xor(s, 2, 64);
    ss += __shfl_xor(ss, 1, 64); ss += __shfl_xor(ss, 2, 64);
    float mu = s * (1.f / 256.f);
    float rs = rsqrtf(ss * (1.f / 256.f) - mu * mu + 1e-5f);
    float ss2 = 0.f;
#pragma unroll
    for (int c = 0; c < 16; ++c) {
        float4 w4 = *(const float4*)&w[(q << 6) + c * 4];
        float4 b4 = *(const float4*)&b[(q << 6) + c * 4];
        v[c].x = (v[c].x - mu) * rs * w4.x + b4.x;
        v[c].y = (v[c].y - mu) * rs * w4.y + b4.y;
        v[c].z = (v[c].z - mu) * rs * w4.z + b4.z;
        v[c].w = (v[c].w - mu) * rs * w4.w + b4.w;
        ss2 += v[c].x * v[c].x + v[c].y * v[c].y + v[c].z * v[c].z + v[c].w * v[c].w;
    }
    ss2 += __shfl_xor(ss2, 1, 64); ss2 += __shfl_xor(ss2, 2, 64);
    float sc = 1.f / fmaxf(sqrtf(ss2), 1e-12f);
    for (int cc = 0; cc < 4; ++cc) {
        if (q == cc) {
#pragma unroll
            for (int c = 0; c < 16; ++c) {
                tile[mo][c * 4 + 0] = v[c].x * sc;
                tile[mo][c * 4 + 1] = v[c].y * sc;
                tile[mo][c * 4 + 2] = v[c].z * sc;
                tile[mo][c * 4 + 3] = v[c].w * sc;
            }
        }
        __syncthreads();
        for (int it = 0; it < 16; ++it) {
            int idx = it * 256 + t;
            int co = idx >> 6, mr = idx & 63;
            out[(size_t)((cc << 6) + co) * M_DIM + m0 + mr] = tile[mr][co];
        }
        __syncthreads();
    }
}

// ---------------------------------------------------------------------------
extern "C" void kernel_launch(void* const* d_in, const int* in_sizes, int n_in,
                              void* d_out, int out_size, void* d_ws, size_t ws_size,
                              hipStream_t stream) {
    const float* grd2sat = (const float*)d_in[0];
    const float* grd_x   = (const float*)d_in[1];
    const float* u       = (const float*)d_in[2];
    const float* ln_q_w  = (const float*)d_in[3];
    const float* ln_q_b  = (const float*)d_in[4];
    const float* ln_k_w  = (const float*)d_in[5];
    const float* ln_k_b  = (const float*)d_in[6];
    const float* ln_v_w  = (const float*)d_in[7];
    const float* ln_v_b  = (const float*)d_in[8];
    const float* Wq      = (const float*)d_in[9];
    const float* Wk      = (const float*)d_in[10];
    const float* Wv      = (const float*)d_in[11];
    const float* Wproj   = (const float*)d_in[12];
    const float* bproj   = (const float*)d_in[13];
    const float* ln_pre_w = (const float*)d_in[14];
    const float* ln_pre_b = (const float*)d_in[15];
    const float* Wm1     = (const float*)d_in[16];
    const float* bm1     = (const float*)d_in[17];
    const float* Wm2     = (const float*)d_in[18];
    const float* bm2     = (const float*)d_in[19];
    const float* ln_post_w = (const float*)d_in[20];
    const float* ln_post_b = (const float*)d_in[21];

    float* ws   = (float*)d_ws;
    float* yhat = ws;                    // 4 MB
    float* xcur = ws + 1048576;          // 4 MB (x, then Z2)
    float* zq   = ws + 2097152;          // 4 MB (Z0 / m1 input)
    float* hbuf = ws + 4194304;          // 8 MB (mlp hidden)
    float* zbuf = ws + 6291456;          // 4 MB (zhat sidecar)
    unsigned short* Qb   = (unsigned short*)(ws + 7340032);  // 2 MB
    unsigned short* Ktab = (unsigned short*)(ws + 7864320);  // 2 MB
    unsigned short* Vt   = (unsigned short*)(ws + 8388608);  // 2 MB
    unsigned short* Bt   = (unsigned short*)(ws + 8912896);  // 4 MB (2 blocks)
    float* biasbuf = ws + 9961472;       // 2560 floats
    int*  perm    = (int*)(ws + 9965568);    // 4096 ints
    int4* chunks  = (int4*)(ws + 9969664);   // 256 int4
    int*  nchunks = (int*)(ws + 9970688);
    const size_t BS = 524288;
    const size_t OQ = 0, OKV = 65536, OP = 196608, OM1 = 262144, OM2 = 393216;

    dim3 b256(256);

    PrepArgs pa;
    pa.grd2sat = grd2sat; pa.xcur = xcur;
    pa.grd_x = grd_x;     pa.yhat = yhat;
    pa.u = u; pa.perm = perm; pa.chunks = chunks; pa.nchunks = nchunks;
    {
        int base = 0;
        for (int i = 0; i < 2; ++i) {
            int e = 6 * i;
            unsigned short* bt = Bt + i * BS;
            pa.win[e+0] = Wq + i * 65536;    pa.wout[e+0] = bt + OQ;
            pa.wlnw[e+0] = ln_q_w + i * 256; pa.wR[e+0] = 256; pa.wC[e+0] = 256;
            pa.win[e+1] = Wk + i * 65536;    pa.wout[e+1] = bt + OKV;
            pa.wlnw[e+1] = ln_k_w + i * 256; pa.wR[e+1] = 256; pa.wC[e+1] = 256;
            pa.win[e+2] = Wv + i * 65536;    pa.wout[e+2] = bt + OKV + 65536;
            pa.wlnw[e+2] = ln_v_w + i * 256; pa.wR[e+2] = 256; pa.wC[e+2] = 256;
            pa.win[e+3] = Wproj + i * 65536; pa.wout[e+3] = bt + OP;
            pa.wlnw[e+3] = nullptr;          pa.wR[e+3] = 256; pa.wC[e+3] = 256;
            pa.win[e+4] = Wm1 + i * 131072;  pa.wout[e+4] = bt + OM1;
            pa.wlnw[e+4] = ln_pre_w + i * 256; pa.wR[e+4] = 256; pa.wC[e+4] = 512;
            pa.win[e+5] = Wm2 + i * 131072;  pa.wout[e+5] = bt + OM2;
            pa.wlnw[e+5] = nullptr;          pa.wR[e+5] = 512; pa.wC[e+5] = 256;
        }
        for (int e = 0; e < 12; ++e) {
            pa.wbase[e] = base;
            base += (pa.wR[e] >> 5) * (pa.wC[e] >> 5);
        }
        pa.wbase[12] = base;  // 1024
        for (int i = 0; i < 2; ++i) {
            int jb = 5 * i;
            float* bb = biasbuf + i * 1280;
            pa.fW[jb+0] = Wq + i * 65536; pa.flnb[jb+0] = ln_q_b + i * 256;
            pa.fbase[jb+0] = nullptr; pa.fout[jb+0] = bb;
            pa.fN[jb+0] = 256; pa.fwcol[jb+0] = 0; pa.focol[jb+0] = 0;
            pa.fW[jb+1] = Wk + i * 65536; pa.flnb[jb+1] = ln_k_b + i * 256;
            pa.fbase[jb+1] = nullptr; pa.fout[jb+1] = bb + 256;
            pa.fN[jb+1] = 256; pa.fwcol[jb+1] = 0; pa.focol[jb+1] = 0;
            pa.fW[jb+2] = Wv + i * 65536; pa.flnb[jb+2] = ln_v_b + i * 256;
            pa.fbase[jb+2] = nullptr; pa.fout[jb+2] = bb + 256;
            pa.fN[jb+2] = 256; pa.fwcol[jb+2] = 0; pa.focol[jb+2] = 256;
            pa.fW[jb+3] = Wm1 + i * 131072; pa.flnb[jb+3] = ln_pre_b + i * 256;
            pa.fbase[jb+3] = bm1 + i * 512; pa.fout[jb+3] = bb + 768;
            pa.fN[jb+3] = 512; pa.fwcol[jb+3] = 0; pa.focol[jb+3] = 0;
            pa.fW[jb+4] = Wm1 + i * 131072; pa.flnb[jb+4] = ln_pre_b + i * 256;
            pa.fbase[jb+4] = bm1 + i * 512; pa.fout[jb+4] = bb + 768;
            pa.fN[jb+4] = 512; pa.fwcol[jb+4] = 256; pa.focol[jb+4] = 256;
        }
    }
    prep_kernel<<<1419, b256, 0, stream>>>(pa);

    for (int i = 0; i < 2; ++i) {
        const unsigned short* bt = Bt + i * BS;
        float* bb = biasbuf + i * 1280;
        GJ jq = {};
        jq.A = xcur; jq.Bt = bt + OQ; jq.bias = bb;
        if (i == 1) { jq.aw = ln_post_w; jq.ab = ln_post_b; }
        jq.out = Qb; jq.K = 256; jq.N = 256;
        GJ jkv = {};
        jkv.A = yhat; jkv.Bt = bt + OKV; jkv.bias = bb + 256;
        jkv.out = Ktab; jkv.out2 = Vt; jkv.K = 256; jkv.N = 512;
        if (i == 0) gemm_mode<0><<<dim3(128, 12), b256, 0, stream>>>(jq, jkv);
        else        gemm_mode<1><<<dim3(128, 12), b256, 0, stream>>>(jq, jkv);

        attn_proj_kernel<<<320, b256, 0, stream>>>(
            Qb, Ktab, Vt, bt + OP, bproj + i * 256, perm, chunks, nchunks, zq);

        GJ jm1 = {};
        jm1.A = zq; jm1.Bt = bt + OM1; jm1.bias = bb + 768;
        jm1.out = hbuf; jm1.wrz = zbuf; jm1.K = 256; jm1.N = 512;
        gemm_mode<3><<<dim3(128, 8), b256, 0, stream>>>(jm1, jm1);

        GJ jm2 = {};
        jm2.A = hbuf; jm2.Bt = bt + OM2; jm2.bias = bm2 + i * 256;
        jm2.res = zbuf; jm2.rw = ln_pre_w + i * 256; jm2.rb = ln_pre_b + i * 256;
        jm2.out = xcur; jm2.K = 512; jm2.N = 256;
        gemm_mode<4><<<dim3(128, 4), b256, 0, stream>>>(jm2, jm2);
    }
    out_kernel<<<64, b256, 0, stream>>>(xcur, ln_post_w + 256, ln_post_b + 256,
                                        (float*)d_out);
}

// Round 7
// 216.382 us; speedup vs baseline: 1.5996x; 1.0720x over previous
//
#include <hip/hip_runtime.h>
#include <math.h>

// ---------------------------------------------------------------------------
// CrossViewAttention — R4 skeleton + lean L2-direct attention + bf16 A GEMMs
// B=1, C=256, M=4096, W=128, H=32, BLOCKS=2, HEADS=8, DH=32
// ---------------------------------------------------------------------------

#define C_DIM 256
#define M_DIM 4096
#define W_DIM 128
#define H_DIM 32
#define ATT_SCALE 0.17677669529663687f  // 1/sqrt(32)

typedef __attribute__((ext_vector_type(8))) short short8;
typedef __attribute__((ext_vector_type(4))) short short4v;
typedef __attribute__((ext_vector_type(4))) float floatx4;

__device__ __forceinline__ unsigned short f2bf(float f) {
    unsigned u = __float_as_uint(f);
    unsigned r = (u + 0x7fffu + ((u >> 16) & 1u)) >> 16;
    return (unsigned short)r;
}
__device__ __forceinline__ float gelu_exact(float x) {
    return 0.5f * x * (1.0f + erff(x * 0.70710678118654752f));
}

// ======================= mega prep kernel ==================================
// roles by blockIdx.x:
//   [0,256)    transpose grd2sat (C,M) -> xcur (M,C)
//   [256,384)  yhat: LN over C of grd_x columns -> yhat[(w*32+h)][c]
//   [384,1408) weight transpose+scale+convert: W'[n][k] = ln_w[k]*W[k][n] bf16
//   [1408,1418) folded biases: out[col] = base[col] + sum_k ln_b[k]*W[k][col]
//   1418       bucket sort of queries by wl=floor(u): perm/chunks/nchunks
struct PrepArgs {
    const float* grd2sat; float* xcur;
    const float* grd_x;   float* yhat;
    const float* u; int* perm; int4* chunks; int* nchunks;
    const float* win[12]; unsigned short* wout[12]; const float* wlnw[12];
    int wR[12], wC[12], wbase[13];
    const float* fW[10]; const float* flnb[10]; const float* fbase[10];
    float* fout[10];
    int fN[10], fwcol[10], focol[10];
};

__global__ __launch_bounds__(256) void prep_kernel(PrepArgs a) {
    __shared__ float smemf[9024];
    int b = blockIdx.x, t = threadIdx.x;
    if (b < 256) {
        float (*tile)[65] = (float(*)[65])smemf;
        int m0 = (b & 63) << 6, c0 = (b >> 6) << 6;
        for (int it = 0; it < 16; ++it) {
            int idx = it * 256 + t;
            int co = idx >> 6, mo = idx & 63;
            tile[co][mo] = a.grd2sat[(size_t)(c0 + co) * M_DIM + m0 + mo];
        }
        __syncthreads();
        for (int it = 0; it < 16; ++it) {
            int idx = it * 256 + t;
            int mo = idx >> 6, co = idx & 63;
            a.xcur[(size_t)(m0 + mo) * C_DIM + c0 + co] = tile[co][mo];
        }
    } else if (b < 384) {
        int idx = b - 256;
        int h = idx & 31, w0 = (idx >> 5) << 5;
        float (*tile)[33] = (float(*)[33])smemf;
        float (*ps)[32] = (float(*)[32])(smemf + 8448);
        float (*pss)[32] = (float(*)[32])(smemf + 8704);
        float* mu_s = smemf + 8960;
        float* rs_s = smemf + 8992;
        int wo = t & 31, cb = t >> 5;
        for (int it = 0; it < 32; ++it) {
            int c = it * 8 + cb;
            tile[c][wo] = a.grd_x[(size_t)c * (H_DIM * W_DIM) + h * W_DIM + w0 + wo];
        }
        __syncthreads();
        {
            int w = t & 31, part = t >> 5;
            float s = 0.f, ss = 0.f;
            for (int c = part * 32; c < part * 32 + 32; ++c) {
                float x = tile[c][w];
                s += x; ss += x * x;
            }
            ps[part][w] = s; pss[part][w] = ss;
        }
        __syncthreads();
        if (t < 32) {
            float s = 0.f, ss = 0.f;
            for (int p = 0; p < 8; ++p) { s += ps[p][t]; ss += pss[p][t]; }
            float mu = s * (1.f / 256.f);
            float var = ss * (1.f / 256.f) - mu * mu;
            mu_s[t] = mu;
            rs_s[t] = rsqrtf(var + 1e-5f);
        }
        __syncthreads();
        for (int jj = 0; jj < 32; ++jj) {
            float mu = mu_s[jj], rs = rs_s[jj];
            a.yhat[((size_t)(w0 + jj) * H_DIM + h) * C_DIM + t] =
                (tile[t][jj] - mu) * rs;
        }
    } else if (b < 1408) {
        int wI = b - 384;
        int e = 0;
        while (wI >= a.wbase[e + 1]) ++e;
        int tl = wI - a.wbase[e];
        int tilesC = a.wC[e] >> 5;
        int tr = tl / tilesC, tc = tl - tr * tilesC;
        int r0 = tr << 5, c0 = tc << 5;
        const float* in = a.win[e];
        unsigned short* out = a.wout[e];
        const float* lnw = a.wlnw[e];
        int R = a.wR[e], Cc = a.wC[e];
        float (*tile)[33] = (float(*)[33])smemf;
        int rl = t >> 3, cq = (t & 7) << 2;
        float4 v = *(const float4*)&in[(size_t)(r0 + rl) * Cc + c0 + cq];
        if (lnw) {
            float s = lnw[r0 + rl];
            v.x *= s; v.y *= s; v.z *= s; v.w *= s;
        }
        tile[rl][cq + 0] = v.x;
        tile[rl][cq + 1] = v.y;
        tile[rl][cq + 2] = v.z;
        tile[rl][cq + 3] = v.w;
        __syncthreads();
        int cl = t >> 3, rq = (t & 7) << 2;
        ushort4 o;
        o.x = f2bf(tile[rq + 0][cl]);
        o.y = f2bf(tile[rq + 1][cl]);
        o.z = f2bf(tile[rq + 2][cl]);
        o.w = f2bf(tile[rq + 3][cl]);
        *(ushort4*)&out[(size_t)(c0 + cl) * R + r0 + rq] = o;
    } else if (b < 1418) {
        int jj = b - 1408;
        int N = a.fN[jj];
        int wcol = a.fwcol[jj] + t;
        const float* W = a.fW[jj];
        const float* lb = a.flnb[jj];
        float s = a.fbase[jj] ? a.fbase[jj][wcol] : 0.f;
        for (int k = 0; k < 256; ++k) s += lb[k] * W[(size_t)k * N + wcol];
        a.fout[jj][a.focol[jj] + t] = s;
    } else {
        // ---- bucket sort by wl = floor(u[m]) in [0,126]; 32-query chunks
        int* hist = (int*)smemf;
        int* cur = (int*)smemf + 128;
        unsigned short* wlb = (unsigned short*)((int*)smemf + 256);
        if (t < 128) hist[t] = 0;
        __syncthreads();
        for (int it = 0; it < 16; ++it) {
            int m = it * 256 + t;
            int wl = (int)floorf(a.u[m]);
            wl = max(0, min(wl, 126));
            wlb[m] = (unsigned short)wl;
            atomicAdd(&hist[wl], 1);
        }
        __syncthreads();
        if (t == 0) {
            int run = 0, nc = 0;
            for (int bkt = 0; bkt < 127; ++bkt) {
                int c = hist[bkt];
                cur[bkt] = run;
                int q0 = run;
                while (c > 0) {
                    int take = min(c, 32);
                    a.chunks[nc] = make_int4(bkt, q0, take, 0);
                    ++nc; q0 += take; c -= take;
                }
                run += hist[bkt];
            }
            *a.nchunks = nc;
        }
        __syncthreads();
        for (int it = 0; it < 16; ++it) {
            int m = it * 256 + t;
            int wl = wlb[m];
            int pos = atomicAdd(&cur[wl], 1);
            a.perm[pos] = m;
        }
    }
}

// ======================= templated MFMA GEMM ===============================
// BM=32, BN=64, 256 threads. A fp32 (or bf16 when ABF16) [M][K]; Bt bf16 [N][K].
// LN: 0 none; 1 plain row-LN; 2 LN->affine(aw,ab)->LN. (fp32 A only)
// EPI: 0 bias; 1 bias+gelu; 2 bias + res*rw+rb.
// OUTM: 0 fp32 [M][N]; 1 bf16 [M][N] (pitch N); 2 split col<256 -> Kt bf16
//       [m][256], col>=256 -> out2 bf16 [(col-256)][4096].
struct GJ {
    const void* A; const unsigned short* Bt;
    const float* bias; const float* aw; const float* ab;
    const float* rw; const float* rb; const float* res;
    float* wrz; void* out; unsigned short* out2;
    int K, N;
};

template <int LN, int EPI, int OUTM, bool WRZ, bool ABF16>
__device__ __forceinline__ void gemm_core(const GJ& j, short (*As)[264],
                                          short (*Bs)[264], int bm, int by) {
    int t = threadIdx.x;
    int bn = by << 6;
    int wv = t >> 6, lane = t & 63;
    int mt = wv & 1, nt0 = (wv >> 1) << 1;
    int quad = lane >> 4, l16 = lane & 15;
    floatx4 acc0 = {0.f, 0.f, 0.f, 0.f};
    floatx4 acc1 = {0.f, 0.f, 0.f, 0.f};
    const int K = j.K;
    for (int kc = 0; kc < K; kc += 256) {
        if (kc) __syncthreads();
        if (ABF16) {
            int ar = t >> 3, cq = (t & 7) << 5;
            const unsigned short* ap =
                (const unsigned short*)j.A + (size_t)(bm + ar) * K + kc + cq;
#pragma unroll
            for (int c = 0; c < 4; ++c)
                *(uint4*)&As[ar][cq + (c << 3)] = *(const uint4*)(ap + (c << 3));
        } else {
            int ar = t >> 3, cq = (t & 7) << 2;
            const float* ap = (const float*)j.A + (size_t)(bm + ar) * K + kc + cq;
            float4 v[8];
#pragma unroll
            for (int g = 0; g < 8; ++g) v[g] = *(const float4*)(ap + g * 32);
            if (LN >= 1) {
                float s = 0.f, ss = 0.f;
#pragma unroll
                for (int g = 0; g < 8; ++g) {
                    s += v[g].x + v[g].y + v[g].z + v[g].w;
                    ss += v[g].x * v[g].x + v[g].y * v[g].y + v[g].z * v[g].z +
                          v[g].w * v[g].w;
                }
#pragma unroll
                for (int o = 1; o < 8; o <<= 1) {
                    s += __shfl_xor(s, o, 64);
                    ss += __shfl_xor(ss, o, 64);
                }
                float mu = s * (1.f / 256.f);
                float rs = rsqrtf(ss * (1.f / 256.f) - mu * mu + 1e-5f);
#pragma unroll
                for (int g = 0; g < 8; ++g) {
                    v[g].x = (v[g].x - mu) * rs;
                    v[g].y = (v[g].y - mu) * rs;
                    v[g].z = (v[g].z - mu) * rs;
                    v[g].w = (v[g].w - mu) * rs;
                }
                if (LN == 2) {
                    float s2 = 0.f, ss2 = 0.f;
#pragma unroll
                    for (int g = 0; g < 8; ++g) {
                        float4 w4 = *(const float4*)(j.aw + cq + g * 32);
                        float4 b4 = *(const float4*)(j.ab + cq + g * 32);
                        v[g].x = v[g].x * w4.x + b4.x;
                        v[g].y = v[g].y * w4.y + b4.y;
                        v[g].z = v[g].z * w4.z + b4.z;
                        v[g].w = v[g].w * w4.w + b4.w;
                        s2 += v[g].x + v[g].y + v[g].z + v[g].w;
                        ss2 += v[g].x * v[g].x + v[g].y * v[g].y +
                               v[g].z * v[g].z + v[g].w * v[g].w;
                    }
#pragma unroll
                    for (int o = 1; o < 8; o <<= 1) {
                        s2 += __shfl_xor(s2, o, 64);
                        ss2 += __shfl_xor(ss2, o, 64);
                    }
                    float mu2 = s2 * (1.f / 256.f);
                    float rs2 = rsqrtf(ss2 * (1.f / 256.f) - mu2 * mu2 + 1e-5f);
#pragma unroll
                    for (int g = 0; g < 8; ++g) {
                        v[g].x = (v[g].x - mu2) * rs2;
                        v[g].y = (v[g].y - mu2) * rs2;
                        v[g].z = (v[g].z - mu2) * rs2;
                        v[g].w = (v[g].w - mu2) * rs2;
                    }
                }
            }
            if (WRZ) {
                if (by == 0) {
#pragma unroll
                    for (int g = 0; g < 8; ++g)
                        *(float4*)&j.wrz[(size_t)(bm + ar) * 256 + cq + g * 32] =
                            v[g];
                }
            }
#pragma unroll
            for (int g = 0; g < 8; ++g) {
                short4v o;
                o[0] = (short)f2bf(v[g].x);
                o[1] = (short)f2bf(v[g].y);
                o[2] = (short)f2bf(v[g].z);
                o[3] = (short)f2bf(v[g].w);
                *(short4v*)&As[ar][cq + g * 32] = o;
            }
        }
        {
            int br = t >> 2, cq2 = (t & 3) << 3;
            const unsigned short* bp = j.Bt + (size_t)(bn + br) * K + kc + cq2;
#pragma unroll
            for (int g = 0; g < 8; ++g)
                *(short8*)&Bs[br][cq2 + g * 32] = *(const short8*)(bp + g * 32);
        }
        __syncthreads();
#pragma unroll
        for (int k0 = 0; k0 < 8; ++k0) {
            short8 aa = *(const short8*)&As[(mt << 4) + l16][(k0 << 5) + (quad << 3)];
            short8 b0 = *(const short8*)&Bs[(nt0 << 4) + l16][(k0 << 5) + (quad << 3)];
            short8 b1 =
                *(const short8*)&Bs[((nt0 + 1) << 4) + l16][(k0 << 5) + (quad << 3)];
            acc0 = __builtin_amdgcn_mfma_f32_16x16x32_bf16(aa, b0, acc0, 0, 0, 0);
            acc1 = __builtin_amdgcn_mfma_f32_16x16x32_bf16(aa, b1, acc1, 0, 0, 0);
        }
    }
#pragma unroll
    for (int jj = 0; jj < 2; ++jj) {
        const floatx4 accv = jj ? acc1 : acc0;
        int col = bn + ((nt0 + jj) << 4) + l16;
        float bv = j.bias ? j.bias[col] : 0.f;
#pragma unroll
        for (int r = 0; r < 4; ++r) {
            int row = bm + (mt << 4) + (quad << 2) + r;
            float v = accv[r] + bv;
            if (EPI == 1) v = gelu_exact(v);
            if (EPI == 2)
                v += j.res[(size_t)row * 256 + col] * j.rw[col] + j.rb[col];
            if (OUTM == 0) {
                ((float*)j.out)[(size_t)row * j.N + col] = v;
            } else if (OUTM == 1) {
                ((unsigned short*)j.out)[(size_t)row * j.N + col] = f2bf(v);
            } else {
                if (col < 256)
                    ((unsigned short*)j.out)[(size_t)row * 256 + col] = f2bf(v);
                else
                    j.out2[(size_t)(col - 256) * M_DIM + row] = f2bf(v);
            }
        }
    }
}

// MODE 0: Q0 (LN=1) + KV0 + KV1 | MODE 1: Q1 (LN=2)
// MODE 2: proj (bf16 A) | MODE 3: m1 (LN+gelu+wrz, bf16 out) | MODE 4: m2
template <int MODE>
__global__ __launch_bounds__(256) void gemm_mode(GJ j0, GJ j1, GJ j2) {
    __shared__ short As[32][264];
    __shared__ short Bs[64][264];
    int bm = blockIdx.x << 5;
    if (MODE == 0) {
        if ((int)blockIdx.y < 4)
            gemm_core<1, 0, 1, false, false>(j0, As, Bs, bm, blockIdx.y);
        else if ((int)blockIdx.y < 12)
            gemm_core<0, 0, 2, false, false>(j1, As, Bs, bm, blockIdx.y - 4);
        else
            gemm_core<0, 0, 2, false, false>(j2, As, Bs, bm, blockIdx.y - 12);
    } else if (MODE == 1) {
        gemm_core<2, 0, 1, false, false>(j0, As, Bs, bm, blockIdx.y);
    } else if (MODE == 2) {
        gemm_core<0, 0, 0, false, true>(j0, As, Bs, bm, blockIdx.y);
    } else if (MODE == 3) {
        gemm_core<1, 1, 1, true, false>(j0, As, Bs, bm, blockIdx.y);
    } else {
        gemm_core<0, 2, 0, false, true>(j0, As, Bs, bm, blockIdx.y);
    }
}

// ======================= lean bucketed MFMA attention ======================
// Grid (chunks, 2): blockIdx.y picks 4 heads. No K/V/Q LDS staging — all MFMA
// fragments are 16B contiguous loads straight from L2. LDS only for the
// S -> softmax -> P round-trip (~14 KB). O written bf16.
__global__ __launch_bounds__(256) void attn_kernel(
    const unsigned short* __restrict__ Qb, const unsigned short* __restrict__ Kt,
    const unsigned short* __restrict__ Vt, const int* __restrict__ perm,
    const int4* __restrict__ chunks, const int* __restrict__ nchunks,
    unsigned short* __restrict__ Ao) {
    __shared__ float S[32][69];
    __shared__ short Pb[32][72];
    __shared__ int gperm[32];
    if ((int)blockIdx.x >= *nchunks) return;
    int4 cd = chunks[blockIdx.x];
    int wl = cd.x, qstart = cd.y, qcnt = cd.z;
    int t = threadIdx.x;
    if (t < 32) gperm[t] = (t < qcnt) ? perm[qstart + t] : perm[qstart];
    __syncthreads();
    int wv = t >> 6, lane = t & 63, quad = lane >> 4, l16 = lane & 15;
    int mt = wv & 1, nt0 = (wv >> 1) << 1;  // scores: q-half, two 16-n tiles
    int ntP = wv >> 1;                       // PV: d-half
    const unsigned short* qp = Qb + (size_t)gperm[(mt << 4) + l16] * 256;
    const unsigned short* kp0 =
        Kt + ((size_t)((wl << 5) + (nt0 << 4) + l16)) * 256;
    const unsigned short* kp1 = kp0 + (16 * 256);
    int sq = t >> 3, sg = t & 7;
    int hb = (int)blockIdx.y << 2;
#pragma unroll 1
    for (int h = hb; h < hb + 4; ++h) {
        {   // scores: S[32 q][64 n]
            short8 aa = *(const short8*)(qp + (h << 5) + (quad << 3));
            short8 b0 = *(const short8*)(kp0 + (h << 5) + (quad << 3));
            short8 b1 = *(const short8*)(kp1 + (h << 5) + (quad << 3));
            floatx4 z = {0.f, 0.f, 0.f, 0.f};
            floatx4 c0 = __builtin_amdgcn_mfma_f32_16x16x32_bf16(aa, b0, z, 0, 0, 0);
            floatx4 c1 = __builtin_amdgcn_mfma_f32_16x16x32_bf16(aa, b1, z, 0, 0, 0);
#pragma unroll
            for (int r = 0; r < 4; ++r) {
                int row = (mt << 4) + (quad << 2) + r;
                S[row][(nt0 << 4) + l16] = c0[r];
                S[row][((nt0 + 1) << 4) + l16] = c1[r];
            }
        }
        __syncthreads();
        {   // softmax row sq over 64 cols; normalized bf16 P
            float e[8];
            float s = 0.f;
#pragma unroll
            for (int c = 0; c < 8; ++c) {
                e[c] = __expf(S[sq][(sg << 3) + c] * ATT_SCALE);
                s += e[c];
            }
            s += __shfl_xor(s, 1, 64);
            s += __shfl_xor(s, 2, 64);
            s += __shfl_xor(s, 4, 64);
            float ri = 1.f / s;
#pragma unroll
            for (int c = 0; c < 8; ++c)
                Pb[sq][(sg << 3) + c] = (short)f2bf(e[c] * ri);
        }
        __syncthreads();
        {   // PV: O[32 q][32 d], V fragments straight from L2
            const unsigned short* vp =
                Vt + ((size_t)((h << 5) + (ntP << 4) + l16)) * M_DIM + (wl << 5);
            floatx4 acc = {0.f, 0.f, 0.f, 0.f};
#pragma unroll
            for (int ks = 0; ks < 2; ++ks) {
                short8 pa =
                    *(const short8*)&Pb[(mt << 4) + l16][(ks << 5) + (quad << 3)];
                short8 vb = *(const short8*)(vp + (ks << 5) + (quad << 3));
                acc = __builtin_amdgcn_mfma_f32_16x16x32_bf16(pa, vb, acc, 0, 0, 0);
            }
#pragma unroll
            for (int r = 0; r < 4; ++r) {
                int q = (mt << 4) + (quad << 2) + r;
                if (q < qcnt)
                    Ao[(size_t)gperm[q] * 256 + (h << 5) + (ntP << 4) + l16] =
                        f2bf(acc[r]);
            }
        }
    }
}

// ======================= final: LN_post + L2 norm + transpose ==============
__global__ __launch_bounds__(256) void out_kernel(const float* __restrict__ X,
                                                  const float* __restrict__ w,
                                                  const float* __restrict__ b,
                                                  float* __restrict__ out) {
    __shared__ float tile[64][65];
    int t = threadIdx.x;
    int mo = t >> 2, q = t & 3;
    int m0 = blockIdx.x << 6;
    const float* p = X + (size_t)(m0 + mo) * C_DIM + (q << 6);
    float4 v[16];
    float s = 0.f, ss = 0.f;
#pragma unroll
    for (int c = 0; c < 16; ++c) {
        v[c] = *(const float4*)(p + c * 4);
        s += v[c].x + v[c].y + v[c].z + v[c].w;
        ss += v[c].x * v[c].x + v[c].y * v[c].y + v[c].z * v[c].z + v[c].w * v[c].w;
    }
    s += __shfl_xor(s, 1, 64); s += __shfl_xor(s, 2, 64);
    ss += __shfl_xor(ss, 1, 64); ss += __shfl_xor(ss, 2, 64);
    float mu = s * (1.f / 256.f);
    float rs = rsqrtf(ss * (1.f / 256.f) - mu * mu + 1e-5f);
    float ss2 = 0.f;
#pragma unroll
    for (int c = 0; c < 16; ++c) {
        float4 w4 = *(const float4*)&w[(q << 6) + c * 4];
        float4 b4 = *(const float4*)&b[(q << 6) + c * 4];
        v[c].x = (v[c].x - mu) * rs * w4.x + b4.x;
        v[c].y = (v[c].y - mu) * rs * w4.y + b4.y;
        v[c].z = (v[c].z - mu) * rs * w4.z + b4.z;
        v[c].w = (v[c].w - mu) * rs * w4.w + b4.w;
        ss2 += v[c].x * v[c].x + v[c].y * v[c].y + v[c].z * v[c].z + v[c].w * v[c].w;
    }
    ss2 += __shfl_xor(ss2, 1, 64); ss2 += __shfl_xor(ss2, 2, 64);
    float sc = 1.f / fmaxf(sqrtf(ss2), 1e-12f);
    for (int cc = 0; cc < 4; ++cc) {
        if (q == cc) {
#pragma unroll
            for (int c = 0; c < 16; ++c) {
                tile[mo][c * 4 + 0] = v[c].x * sc;
                tile[mo][c * 4 + 1] = v[c].y * sc;
                tile[mo][c * 4 + 2] = v[c].z * sc;
                tile[mo][c * 4 + 3] = v[c].w * sc;
            }
        }
        __syncthreads();
        for (int it = 0; it < 16; ++it) {
            int idx = it * 256 + t;
            int co = idx >> 6, mr = idx & 63;
            out[(size_t)((cc << 6) + co) * M_DIM + m0 + mr] = tile[mr][co];
        }
        __syncthreads();
    }
}

// ---------------------------------------------------------------------------
extern "C" void kernel_launch(void* const* d_in, const int* in_sizes, int n_in,
                              void* d_out, int out_size, void* d_ws, size_t ws_size,
                              hipStream_t stream) {
    const float* grd2sat = (const float*)d_in[0];
    const float* grd_x   = (const float*)d_in[1];
    const float* u       = (const float*)d_in[2];
    const float* ln_q_w  = (const float*)d_in[3];
    const float* ln_q_b  = (const float*)d_in[4];
    const float* ln_k_w  = (const float*)d_in[5];
    const float* ln_k_b  = (const float*)d_in[6];
    const float* ln_v_w  = (const float*)d_in[7];
    const float* ln_v_b  = (const float*)d_in[8];
    const float* Wq      = (const float*)d_in[9];
    const float* Wk      = (const float*)d_in[10];
    const float* Wv      = (const float*)d_in[11];
    const float* Wproj   = (const float*)d_in[12];
    const float* bproj   = (const float*)d_in[13];
    const float* ln_pre_w = (const float*)d_in[14];
    const float* ln_pre_b = (const float*)d_in[15];
    const float* Wm1     = (const float*)d_in[16];
    const float* bm1     = (const float*)d_in[17];
    const float* Wm2     = (const float*)d_in[18];
    const float* bm2     = (const float*)d_in[19];
    const float* ln_post_w = (const float*)d_in[20];
    const float* ln_post_b = (const float*)d_in[21];

    float* ws   = (float*)d_ws;
    float* yhat = ws;                        // 4 MB
    float* xcur = ws + 1048576;              // 4 MB (x, then Z2)
    float* zq   = ws + 2097152;              // 4 MB (Z0, fp32)
    float* zbuf = ws + 3145728;              // 4 MB (z-hat sidecar fp32)
    unsigned short* hbuf = (unsigned short*)(ws + 4194304);  // 4 MB bf16 [4096][512]
    unsigned short* Qb   = (unsigned short*)(ws + 5242880);  // 2 MB
    unsigned short* abuf = (unsigned short*)(ws + 5767168);  // 2 MB
    unsigned short* Ktab0 = (unsigned short*)(ws + 6291456); // 2 MB
    unsigned short* Vt0   = (unsigned short*)(ws + 6815744); // 2 MB
    unsigned short* Ktab1 = (unsigned short*)(ws + 7340032); // 2 MB
    unsigned short* Vt1   = (unsigned short*)(ws + 7864320); // 2 MB
    unsigned short* Bt    = (unsigned short*)(ws + 8388608); // 2 MB (both blocks)
    float* biasbuf = ws + 8912896;           // 2560 floats
    int*  perm    = (int*)(ws + 8915456);    // 4096 ints
    int4* chunks  = (int4*)(ws + 8919552);   // 512 int4
    int*  nchunks = (int*)(ws + 8921600);
    const size_t BS = 524288;
    const size_t OQ = 0, OKV = 65536, OP = 196608, OM1 = 262144, OM2 = 393216;

    dim3 b256(256);

    PrepArgs pa;
    pa.grd2sat = grd2sat; pa.xcur = xcur;
    pa.grd_x = grd_x;     pa.yhat = yhat;
    pa.u = u; pa.perm = perm; pa.chunks = chunks; pa.nchunks = nchunks;
    {
        int base = 0;
        for (int i = 0; i < 2; ++i) {
            int e = 6 * i;
            unsigned short* bt = Bt + i * BS;
            pa.win[e+0] = Wq + i * 65536;    pa.wout[e+0] = bt + OQ;
            pa.wlnw[e+0] = ln_q_w + i * 256; pa.wR[e+0] = 256; pa.wC[e+0] = 256;
            pa.win[e+1] = Wk + i * 65536;    pa.wout[e+1] = bt + OKV;
            pa.wlnw[e+1] = ln_k_w + i * 256; pa.wR[e+1] = 256; pa.wC[e+1] = 256;
            pa.win[e+2] = Wv + i * 65536;    pa.wout[e+2] = bt + OKV + 65536;
            pa.wlnw[e+2] = ln_v_w + i * 256; pa.wR[e+2] = 256; pa.wC[e+2] = 256;
            pa.win[e+3] = Wproj + i * 65536; pa.wout[e+3] = bt + OP;
            pa.wlnw[e+3] = nullptr;          pa.wR[e+3] = 256; pa.wC[e+3] = 256;
            pa.win[e+4] = Wm1 + i * 131072;  pa.wout[e+4] = bt + OM1;
            pa.wlnw[e+4] = ln_pre_w + i * 256; pa.wR[e+4] = 256; pa.wC[e+4] = 512;
            pa.win[e+5] = Wm2 + i * 131072;  pa.wout[e+5] = bt + OM2;
            pa.wlnw[e+5] = nullptr;          pa.wR[e+5] = 512; pa.wC[e+5] = 256;
        }
        for (int e = 0; e < 12; ++e) {
            pa.wbase[e] = base;
            base += (pa.wR[e] >> 5) * (pa.wC[e] >> 5);
        }
        pa.wbase[12] = base;  // 1024
        for (int i = 0; i < 2; ++i) {
            int jb = 5 * i;
            float* bb = biasbuf + i * 1280;
            pa.fW[jb+0] = Wq + i * 65536; pa.flnb[jb+0] = ln_q_b + i * 256;
            pa.fbase[jb+0] = nullptr; pa.fout[jb+0] = bb;
            pa.fN[jb+0] = 256; pa.fwcol[jb+0] = 0; pa.focol[jb+0] = 0;
            pa.fW[jb+1] = Wk + i * 65536; pa.flnb[jb+1] = ln_k_b + i * 256;
            pa.fbase[jb+1] = nullptr; pa.fout[jb+1] = bb + 256;
            pa.fN[jb+1] = 256; pa.fwcol[jb+1] = 0; pa.focol[jb+1] = 0;
            pa.fW[jb+2] = Wv + i * 65536; pa.flnb[jb+2] = ln_v_b + i * 256;
            pa.fbase[jb+2] = nullptr; pa.fout[jb+2] = bb + 256;
            pa.fN[jb+2] = 256; pa.fwcol[jb+2] = 0; pa.focol[jb+2] = 256;
            pa.fW[jb+3] = Wm1 + i * 131072; pa.flnb[jb+3] = ln_pre_b + i * 256;
            pa.fbase[jb+3] = bm1 + i * 512; pa.fout[jb+3] = bb + 768;
            pa.fN[jb+3] = 512; pa.fwcol[jb+3] = 0; pa.focol[jb+3] = 0;
            pa.fW[jb+4] = Wm1 + i * 131072; pa.flnb[jb+4] = ln_pre_b + i * 256;
            pa.fbase[jb+4] = bm1 + i * 512; pa.fout[jb+4] = bb + 768;
            pa.fN[jb+4] = 512; pa.fwcol[jb+4] = 256; pa.focol[jb+4] = 256;
        }
    }
    prep_kernel<<<1419, b256, 0, stream>>>(pa);

    GJ jz = {};
    for (int i = 0; i < 2; ++i) {
        const unsigned short* bt = Bt + i * BS;
        float* bb = biasbuf + i * 1280;
        unsigned short* Kt = i ? Ktab1 : Ktab0;
        unsigned short* Vt = i ? Vt1 : Vt0;

        GJ jq = {};
        jq.A = xcur; jq.Bt = bt + OQ; jq.bias = bb;
        if (i == 1) { jq.aw = ln_post_w; jq.ab = ln_post_b; }
        jq.out = Qb; jq.K = 256; jq.N = 256;
        if (i == 0) {
            GJ jkv0 = {};
            jkv0.A = yhat; jkv0.Bt = Bt + OKV; jkv0.bias = biasbuf + 256;
            jkv0.out = Ktab0; jkv0.out2 = Vt0; jkv0.K = 256; jkv0.N = 512;
            GJ jkv1 = {};
            jkv1.A = yhat; jkv1.Bt = Bt + BS + OKV; jkv1.bias = biasbuf + 1280 + 256;
            jkv1.out = Ktab1; jkv1.out2 = Vt1; jkv1.K = 256; jkv1.N = 512;
            gemm_mode<0><<<dim3(128, 20), b256, 0, stream>>>(jq, jkv0, jkv1);
        } else {
            gemm_mode<1><<<dim3(128, 4), b256, 0, stream>>>(jq, jz, jz);
        }

        attn_kernel<<<dim3(384, 2), b256, 0, stream>>>(Qb, Kt, Vt, perm, chunks,
                                                       nchunks, abuf);

        GJ jp = {};
        jp.A = abuf; jp.Bt = bt + OP; jp.bias = bproj + i * 256;
        jp.out = zq; jp.K = 256; jp.N = 256;
        gemm_mode<2><<<dim3(128, 4), b256, 0, stream>>>(jp, jz, jz);

        GJ jm1 = {};
        jm1.A = zq; jm1.Bt = bt + OM1; jm1.bias = bb + 768;
        jm1.out = hbuf; jm1.wrz = zbuf; jm1.K = 256; jm1.N = 512;
        gemm_mode<3><<<dim3(128, 8), b256, 0, stream>>>(jm1, jz, jz);

        GJ jm2 = {};
        jm2.A = hbuf; jm2.Bt = bt + OM2; jm2.bias = bm2 + i * 256;
        jm2.res = zbuf; jm2.rw = ln_pre_w + i * 256; jm2.rb = ln_pre_b + i * 256;
        jm2.out = xcur; jm2.K = 512; jm2.N = 256;
        gemm_mode<4><<<dim3(128, 4), b256, 0, stream>>>(jm2, jz, jz);
    }
    out_kernel<<<64, b256, 0, stream>>>(xcur, ln_post_w + 256, ln_post_b + 256,
                                        (float*)d_out);
}